// Round 1
// baseline (1798.744 us; speedup 1.0000x reference)
//
#include <hip/hip_runtime.h>
#include <hip/hip_bf16.h>

typedef unsigned short u16;
typedef short s16x8 __attribute__((ext_vector_type(8)));
typedef float f32x4 __attribute__((ext_vector_type(4)));
typedef int   i32x4 __attribute__((ext_vector_type(4)));
typedef u16   u16x4 __attribute__((ext_vector_type(4)));

#define HEADS  24
#define HD     128
#define HIDDEN 3072
#define MLPD   12288
#define NTOK   2304
#define SIMG   2048
#define NEMB   9216
#define LN_EPS 1e-6f

__device__ __forceinline__ u16 f2us(float f){
  __hip_bfloat16 h = __float2bfloat16(f);
  return *reinterpret_cast<u16*>(&h);
}
__device__ __forceinline__ float us2f(u16 u){
  __hip_bfloat16 h;
  *reinterpret_cast<u16*>(&h) = u;
  return __bfloat162float(h);
}
__device__ __forceinline__ float gelu_tanh(float x){
  float x3 = x*x*x;
  float t = tanhf(0.7978845608028654f*(x + 0.044715f*x3));
  return 0.5f*x*(1.0f + t);
}

// ---------------------------------------------------------------- emb kernel
__global__ __launch_bounds__(256)
void emb_kernel(const float* __restrict__ temb, const float* __restrict__ wn,
                const float* __restrict__ bn, float* __restrict__ emb)
{
  __shared__ float ls[HIDDEN];
  int tid = threadIdx.x;
  for (int i = tid; i < HIDDEN; i += 256){
    float t = temb[i];
    ls[i] = t / (1.0f + __expf(-t));   // silu
  }
  __syncthreads();
  int j = blockIdx.x*256 + tid;
  const float* wp = wn + j;
  float acc = bn[j];
  #pragma unroll 8
  for (int i = 0; i < HIDDEN; i++){
    acc = fmaf(ls[i], wp[0], acc);
    wp += NEMB;
  }
  emb[j] = acc;
}

// ------------------------------------------------- layernorm + modulate (bf16)
__global__ __launch_bounds__(256)
void ln_mod(const float* __restrict__ hs, const float* __restrict__ ehs,
            const float* __restrict__ emb, u16* __restrict__ nx)
{
  int row = blockIdx.x;
  const float* x = (row < SIMG) ? hs + (size_t)row*HIDDEN
                                : ehs + (size_t)(row - SIMG)*HIDDEN;
  int tid = threadIdx.x;
  float vals[12];
  float s = 0.f, ss = 0.f;
  #pragma unroll
  for (int i = 0; i < 3; i++){
    float4 v = *reinterpret_cast<const float4*>(x + i*1024 + tid*4);
    vals[i*4+0]=v.x; vals[i*4+1]=v.y; vals[i*4+2]=v.z; vals[i*4+3]=v.w;
    s += v.x+v.y+v.z+v.w;
    ss += v.x*v.x + v.y*v.y + v.z*v.z + v.w*v.w;
  }
  #pragma unroll
  for (int d = 1; d < 64; d <<= 1){ s += __shfl_xor(s, d); ss += __shfl_xor(ss, d); }
  __shared__ float red[8];
  if ((tid & 63) == 0){ red[tid>>6] = s; red[4 + (tid>>6)] = ss; }
  __syncthreads();
  s  = red[0]+red[1]+red[2]+red[3];
  ss = red[4]+red[5]+red[6]+red[7];
  float mu = s * (1.0f/HIDDEN);
  float var = ss * (1.0f/HIDDEN) - mu*mu;
  float rs = rsqrtf(var + LN_EPS);
  #pragma unroll
  for (int i = 0; i < 3; i++){
    int col = i*1024 + tid*4;
    u16x4 o;
    #pragma unroll
    for (int j = 0; j < 4; j++){
      float nv = (vals[i*4+j] - mu) * rs;
      float outv = nv * (1.0f + emb[HIDDEN + col + j]) + emb[col + j];
      o[j] = f2us(outv);
    }
    *reinterpret_cast<u16x4*>(nx + (size_t)row*HIDDEN + col) = o;
  }
}

// ------------------------------------------------------------- generic GEMM
// C[M x N] = A[M x K](bf16, optionally split in K across two buffers) * W[K x N](f32)
// EPI 0: out = bf16(acc + bias)
// EPI 1: out = bf16(gelu(acc + bias))
// EPI 2: out = f32( gate[col]*(acc + bias[col]) + residual[row][col] )
template<int EPI>
__global__ __launch_bounds__(256)
void gemm_bf16(const u16* __restrict__ A, const u16* __restrict__ A2,
               int Ksplit, int sA1, int sA2,
               const float* __restrict__ W, const float* __restrict__ bias,
               u16* __restrict__ outb, float* __restrict__ outf,
               int K, int N,
               const float* __restrict__ emb,
               const float* __restrict__ hs, const float* __restrict__ ehs)
{
  __shared__ __align__(16) u16 As[128][48];   // pad: stride 96B (16B-mult)
  __shared__ __align__(16) u16 Bt[128][56];   // transposed W tile, swizzled k-blocks

  const int tid = threadIdx.x;
  const int lane = tid & 63, wid = tid >> 6;
  const int wm = wid >> 1, wn = wid & 1;
  const int m0 = blockIdx.y * 128, n0 = blockIdx.x * 128;
  const int l15 = lane & 15, lhi = lane >> 4;

  f32x4 acc[4][4];
  #pragma unroll
  for (int i = 0; i < 4; i++)
    #pragma unroll
    for (int j = 0; j < 4; j++){ f32x4 z = {0.f,0.f,0.f,0.f}; acc[i][j] = z; }

  for (int k0 = 0; k0 < K; k0 += 32){
    const u16* Ab; int Ast; int kb;
    if (k0 < Ksplit){ Ab = A;  Ast = sA1; kb = k0; }
    else            { Ab = A2; Ast = sA2; kb = k0 - Ksplit; }

    // stage A: 128 rows x 32 k (bf16), 512 chunks of 8 elems
    #pragma unroll
    for (int i = 0; i < 2; i++){
      int c = tid + 256*i;
      int row = c >> 2, ko = (c & 3) * 8;
      i32x4 v = *reinterpret_cast<const i32x4*>(Ab + (size_t)(m0+row)*Ast + kb + ko);
      *reinterpret_cast<i32x4*>(&As[row][ko]) = v;
    }
    // stage W transposed: 32 k x 128 n, convert f32->bf16, swizzled k-blocks
    #pragma unroll
    for (int i = 0; i < 4; i++){
      int c = tid + 256*i;
      int k = c >> 5, n4 = (c & 31) * 4;
      float4 wv = *reinterpret_cast<const float4*>(W + (size_t)(k0+k)*N + n0 + n4);
      const float* wf = reinterpret_cast<const float*>(&wv);
      #pragma unroll
      for (int j = 0; j < 4; j++){
        int n = n4 + j;
        int col = (((k>>3) ^ ((n>>3)&3)) << 3) | (k & 7);
        Bt[n][col] = f2us(wf[j]);
      }
    }
    __syncthreads();

    s16x8 af[4], bfr[4];
    #pragma unroll
    for (int mf = 0; mf < 4; mf++){
      int row = wm*64 + mf*16 + l15;
      af[mf] = *reinterpret_cast<const s16x8*>(&As[row][lhi*8]);
    }
    #pragma unroll
    for (int nf = 0; nf < 4; nf++){
      int n = wn*64 + nf*16 + l15;
      int cb = (lhi ^ ((n>>3)&3)) << 3;
      bfr[nf] = *reinterpret_cast<const s16x8*>(&Bt[n][cb]);
    }
    #pragma unroll
    for (int mf = 0; mf < 4; mf++)
      #pragma unroll
      for (int nf = 0; nf < 4; nf++)
        acc[mf][nf] = __builtin_amdgcn_mfma_f32_16x16x32_bf16(af[mf], bfr[nf], acc[mf][nf], 0, 0, 0);
    __syncthreads();
  }

  // epilogue
  #pragma unroll
  for (int mf = 0; mf < 4; mf++){
    #pragma unroll
    for (int nf = 0; nf < 4; nf++){
      #pragma unroll
      for (int r = 0; r < 4; r++){
        int row = m0 + wm*64 + mf*16 + lhi*4 + r;
        int col = n0 + wn*64 + nf*16 + l15;
        float vv = acc[mf][nf][r] + bias[col];
        if constexpr (EPI == 0){
          outb[(size_t)row*N + col] = f2us(vv);
        } else if constexpr (EPI == 1){
          outb[(size_t)row*N + col] = f2us(gelu_tanh(vv));
        } else {
          float res = (row < SIMG) ? hs[(size_t)row*HIDDEN + col]
                                   : ehs[(size_t)(row-SIMG)*HIDDEN + col];
          outf[(size_t)row*HIDDEN + col] = emb[2*HIDDEN + col] * vv + res;
        }
      }
    }
  }
}

// ------------------------------------------- rmsnorm + rope on q,k (in place)
__global__ __launch_bounds__(256)
void qk_post(u16* __restrict__ q, u16* __restrict__ k,
             const float* __restrict__ nqw, const float* __restrict__ nkw,
             const float* __restrict__ fc)
{
  int rid = blockIdx.x*4 + (threadIdx.x >> 6);
  int lane = threadIdx.x & 63;
  int isK = rid >= NTOK*HEADS;
  int r = isK ? rid - NTOK*HEADS : rid;
  int token = r / HEADS, head = r % HEADS;
  u16* p = (isK ? k : q) + (size_t)token*HIDDEN + head*HD + lane*2;
  unsigned int u = *reinterpret_cast<unsigned int*>(p);
  float v0 = us2f((u16)(u & 0xffff));
  float v1 = us2f((u16)(u >> 16));
  float ss = v0*v0 + v1*v1;
  #pragma unroll
  for (int d = 1; d < 64; d <<= 1) ss += __shfl_xor(ss, d);
  float rs = rsqrtf(ss * (1.0f/HD) + LN_EPS);
  const float* wv = isK ? nkw : nqw;
  v0 *= rs * wv[lane*2];
  v1 *= rs * wv[lane*2+1];
  if (token < SIMG){
    const float* f = fc + (size_t)token*(2*HD);
    float c0 = f[lane*2],      c1 = f[lane*2+1];
    float s0 = f[HD + lane*2], s1 = f[HD + lane*2+1];
    float o0 = v0*c0 - v1*s0;
    float o1 = v1*c1 + v0*s1;
    v0 = o0; v1 = o1;
  }
  unsigned int uo = (unsigned int)f2us(v0) | ((unsigned int)f2us(v1) << 16);
  *reinterpret_cast<unsigned int*>(p) = uo;
}

// ------------------------------------------------------------ flash attention
__global__ __launch_bounds__(256)
void attn_kernel(const u16* __restrict__ q, const u16* __restrict__ k,
                 const u16* __restrict__ v, u16* __restrict__ o)
{
  __shared__ __align__(16) u16 Qs[64][136];
  __shared__ __align__(16) u16 Ks[64][136];
  __shared__ __align__(16) u16 Vt[128][72];  // transposed V, swizzled kv-blocks
  __shared__ __align__(16) u16 Ps[64][72];   // P, swizzled kv-blocks

  const int tid = threadIdx.x, lane = tid & 63, w = tid >> 6;
  const int head = blockIdx.y, qb = blockIdx.x;
  const int l15 = lane & 15, lhi = lane >> 4;
  const int q0 = qb * 64;
  const float scale = 0.08838834764831845f;  // 1/sqrt(128)

  #pragma unroll
  for (int i = 0; i < 4; i++){
    int c = tid + 256*i;
    int row = c >> 4, d0 = (c & 15) * 8;
    i32x4 vv = *reinterpret_cast<const i32x4*>(q + (size_t)(q0+row)*HIDDEN + head*HD + d0);
    *reinterpret_cast<i32x4*>(&Qs[row][d0]) = vv;
  }

  f32x4 O[8];
  #pragma unroll
  for (int i = 0; i < 8; i++){ f32x4 z = {0.f,0.f,0.f,0.f}; O[i] = z; }
  float mrow[4], lrow[4];
  #pragma unroll
  for (int r = 0; r < 4; r++){ mrow[r] = -1e30f; lrow[r] = 0.f; }

  for (int kv0 = 0; kv0 < NTOK; kv0 += 64){
    // stage K tile
    #pragma unroll
    for (int i = 0; i < 4; i++){
      int c = tid + 256*i;
      int row = c >> 4, d0 = (c & 15) * 8;
      i32x4 vv = *reinterpret_cast<const i32x4*>(k + (size_t)(kv0+row)*HIDDEN + head*HD + d0);
      *reinterpret_cast<i32x4*>(&Ks[row][d0]) = vv;
    }
    // stage V transposed
    #pragma unroll
    for (int i = 0; i < 4; i++){
      int c = tid + 256*i;
      int kvr = c >> 4, d0 = (c & 15) * 8;
      i32x4 vv = *reinterpret_cast<const i32x4*>(v + (size_t)(kv0+kvr)*HIDDEN + head*HD + d0);
      const u16* pv = reinterpret_cast<const u16*>(&vv);
      #pragma unroll
      for (int j = 0; j < 8; j++){
        int d = d0 + j;
        int col = (((kvr>>3) ^ ((d>>3)&7)) << 3) | (kvr & 7);
        Vt[d][col] = pv[j];
      }
    }
    __syncthreads();

    // S = Q K^T (this wave: rows w*16..w*16+15 x 64 kv)
    f32x4 S[4];
    #pragma unroll
    for (int nf = 0; nf < 4; nf++){ f32x4 z = {0.f,0.f,0.f,0.f}; S[nf] = z; }
    #pragma unroll
    for (int ks = 0; ks < 4; ks++){
      s16x8 a = *reinterpret_cast<const s16x8*>(&Qs[w*16 + l15][ks*32 + lhi*8]);
      #pragma unroll
      for (int nf = 0; nf < 4; nf++){
        s16x8 b = *reinterpret_cast<const s16x8*>(&Ks[nf*16 + l15][ks*32 + lhi*8]);
        S[nf] = __builtin_amdgcn_mfma_f32_16x16x32_bf16(a, b, S[nf], 0, 0, 0);
      }
    }
    #pragma unroll
    for (int nf = 0; nf < 4; nf++)
      #pragma unroll
      for (int r = 0; r < 4; r++) S[nf][r] *= scale;

    // online softmax (rows: (lhi*4 + r) within this wave's strip)
    float fsc[4];
    #pragma unroll
    for (int r = 0; r < 4; r++){
      float mx = -1e30f;
      #pragma unroll
      for (int nf = 0; nf < 4; nf++) mx = fmaxf(mx, S[nf][r]);
      #pragma unroll
      for (int d = 1; d < 16; d <<= 1) mx = fmaxf(mx, __shfl_xor(mx, d));
      float mn = fmaxf(mrow[r], mx);
      float f = __expf(mrow[r] - mn);
      mrow[r] = mn; fsc[r] = f;
      float lsum = 0.f;
      int prow = w*16 + lhi*4 + r;
      #pragma unroll
      for (int nf = 0; nf < 4; nf++){
        float pvl = __expf(S[nf][r] - mn);
        lsum += pvl;
        int pcol = nf*16 + l15;
        int col = (((pcol>>3) ^ (prow&7)) << 3) | (pcol & 7);
        Ps[prow][col] = f2us(pvl);
      }
      #pragma unroll
      for (int d = 1; d < 16; d <<= 1) lsum += __shfl_xor(lsum, d);
      lrow[r] = lrow[r]*f + lsum;
    }
    #pragma unroll
    for (int nf = 0; nf < 8; nf++)
      #pragma unroll
      for (int r = 0; r < 4; r++) O[nf][r] *= fsc[r];
    __syncthreads();

    // O += P V
    #pragma unroll
    for (int ks = 0; ks < 2; ks++){
      int prow = w*16 + l15;
      int cb = ((ks*4 + lhi) ^ (prow & 7)) << 3;
      s16x8 a = *reinterpret_cast<const s16x8*>(&Ps[prow][cb]);
      #pragma unroll
      for (int nf = 0; nf < 8; nf++){
        int d = nf*16 + l15;
        int vb = ((ks*4 + lhi) ^ ((d>>3)&7)) << 3;
        s16x8 b = *reinterpret_cast<const s16x8*>(&Vt[d][vb]);
        O[nf] = __builtin_amdgcn_mfma_f32_16x16x32_bf16(a, b, O[nf], 0, 0, 0);
      }
    }
    __syncthreads();
  }

  #pragma unroll
  for (int nf = 0; nf < 8; nf++){
    #pragma unroll
    for (int r = 0; r < 4; r++){
      int row = q0 + w*16 + lhi*4 + r;
      int col = head*HD + nf*16 + l15;
      o[(size_t)row*HIDDEN + col] = f2us(O[nf][r] / lrow[r]);
    }
  }
}

// ---------------------------------------------------------------------- host
extern "C" void kernel_launch(void* const* d_in, const int* in_sizes, int n_in,
                              void* d_out, int out_size, void* d_ws, size_t ws_size,
                              hipStream_t stream)
{
  const float* hs    = (const float*)d_in[0];
  const float* ehs   = (const float*)d_in[1];
  const float* temb  = (const float*)d_in[2];
  const float* fc    = (const float*)d_in[3];
  const float* wnorm = (const float*)d_in[4];
  const float* bnorm = (const float*)d_in[5];
  const float* wq    = (const float*)d_in[6];
  const float* bq    = (const float*)d_in[7];
  const float* wk    = (const float*)d_in[8];
  const float* bk    = (const float*)d_in[9];
  const float* wv    = (const float*)d_in[10];
  const float* bv    = (const float*)d_in[11];
  const float* nqw   = (const float*)d_in[12];
  const float* nkw   = (const float*)d_in[13];
  const float* wmlp  = (const float*)d_in[14];
  const float* bmlp  = (const float*)d_in[15];
  const float* wout  = (const float*)d_in[16];
  const float* bout  = (const float*)d_in[17];
  float* outp = (float*)d_out;

  char* ws = (char*)d_ws;
  float* emb = (float*)ws;                             // 9216 f32
  u16* nx    = (u16*)(ws + 36864);
  u16* qb    = nx + (size_t)NTOK*HIDDEN;
  u16* kb    = qb + (size_t)NTOK*HIDDEN;
  u16* vb    = kb + (size_t)NTOK*HIDDEN;
  u16* mlp   = vb + (size_t)NTOK*HIDDEN;
  u16* attnb = mlp + (size_t)NTOK*MLPD;

  emb_kernel<<<NEMB/256, 256, 0, stream>>>(temb, wnorm, bnorm, emb);
  ln_mod<<<NTOK, 256, 0, stream>>>(hs, ehs, emb, nx);

  dim3 g1(HIDDEN/128, NTOK/128);
  gemm_bf16<0><<<g1, 256, 0, stream>>>(nx, nx, HIDDEN, HIDDEN, HIDDEN, wq, bq, qb, nullptr, HIDDEN, HIDDEN, nullptr, nullptr, nullptr);
  gemm_bf16<0><<<g1, 256, 0, stream>>>(nx, nx, HIDDEN, HIDDEN, HIDDEN, wk, bk, kb, nullptr, HIDDEN, HIDDEN, nullptr, nullptr, nullptr);
  gemm_bf16<0><<<g1, 256, 0, stream>>>(nx, nx, HIDDEN, HIDDEN, HIDDEN, wv, bv, vb, nullptr, HIDDEN, HIDDEN, nullptr, nullptr, nullptr);
  dim3 g2(MLPD/128, NTOK/128);
  gemm_bf16<1><<<g2, 256, 0, stream>>>(nx, nx, HIDDEN, HIDDEN, HIDDEN, wmlp, bmlp, mlp, nullptr, HIDDEN, MLPD, nullptr, nullptr, nullptr);

  qk_post<<<(2*NTOK*HEADS)/4, 256, 0, stream>>>(qb, kb, nqw, nkw, fc);

  dim3 ga(NTOK/64, HEADS);
  attn_kernel<<<ga, 256, 0, stream>>>(qb, kb, vb, attnb);

  dim3 g3(HIDDEN/128, NTOK/128);
  gemm_bf16<2><<<g3, 256, 0, stream>>>(attnb, mlp, HIDDEN, HIDDEN, MLPD, wout, bout, nullptr, outp, HIDDEN+MLPD, HIDDEN, emb, hs, ehs);
}

// Round 2
// 1274.340 us; speedup vs baseline: 1.4115x; 1.4115x over previous
//
#include <hip/hip_runtime.h>
#include <hip/hip_bf16.h>

typedef unsigned short u16;
typedef short s16x8 __attribute__((ext_vector_type(8)));
typedef float f32x4 __attribute__((ext_vector_type(4)));
typedef int   i32x4 __attribute__((ext_vector_type(4)));
typedef u16   u16x4 __attribute__((ext_vector_type(4)));

#define HEADS  24
#define HD     128
#define HIDDEN 3072
#define MLPD   12288
#define NTOK   2304
#define SIMG   2048
#define NEMB   9216
#define CATD   15360   // HIDDEN + MLPD
#define QKVD   9216    // 3*HIDDEN
#define LN_EPS 1e-6f

__device__ __forceinline__ u16 f2us(float f){
  __hip_bfloat16 h = __float2bfloat16(f);
  return *reinterpret_cast<u16*>(&h);
}
__device__ __forceinline__ float us2f(u16 u){
  __hip_bfloat16 h;
  *reinterpret_cast<u16*>(&h) = u;
  return __bfloat162float(h);
}
__device__ __forceinline__ float gelu_tanh(float x){
  float y = 0.7978845608028654f*(x + 0.044715f*x*x*x);
  y = fminf(fmaxf(y, -12.f), 12.f);
  float e = __expf(-2.f*y);
  float t = (1.f - e) / (1.f + e);
  return 0.5f*x*(1.0f + t);
}
__device__ __forceinline__ void gload16(const u16* g, const u16* l){
  __builtin_amdgcn_global_load_lds(
      (const __attribute__((address_space(1))) void*)g,
      (__attribute__((address_space(3))) void*)l, 16, 0, 0);
}

// ---------------------------------------------------------------- emb kernels
__global__ __launch_bounds__(256)
void emb_partial(const float* __restrict__ temb, const float* __restrict__ wn,
                 float* __restrict__ partial)
{
  __shared__ float ls[384];
  int tid = threadIdx.x;
  int kb = blockIdx.y * 384;
  for (int i = tid; i < 384; i += 256){
    float t = temb[kb + i];
    ls[i] = t / (1.0f + __expf(-t));
  }
  __syncthreads();
  int j = blockIdx.x*256 + tid;
  const float* wp = wn + (size_t)kb*NEMB + j;
  float acc = 0.f;
  #pragma unroll 8
  for (int i = 0; i < 384; i++){ acc = fmaf(ls[i], wp[0], acc); wp += NEMB; }
  partial[blockIdx.y*NEMB + j] = acc;
}

__global__ __launch_bounds__(256)
void emb_reduce(const float* __restrict__ partial, const float* __restrict__ bn,
                float* __restrict__ emb)
{
  int j = blockIdx.x*256 + threadIdx.x;
  float s = bn[j];
  #pragma unroll
  for (int r = 0; r < 8; r++) s += partial[r*NEMB + j];
  emb[j] = s;
}

// ------------------------------------------------- layernorm + modulate (bf16)
__global__ __launch_bounds__(256)
void ln_mod(const float* __restrict__ hs, const float* __restrict__ ehs,
            const float* __restrict__ emb, u16* __restrict__ nx)
{
  int row = blockIdx.x;
  const float* x = (row < SIMG) ? hs + (size_t)row*HIDDEN
                                : ehs + (size_t)(row - SIMG)*HIDDEN;
  int tid = threadIdx.x;
  float vals[12];
  float s = 0.f, ss = 0.f;
  #pragma unroll
  for (int i = 0; i < 3; i++){
    float4 v = *reinterpret_cast<const float4*>(x + i*1024 + tid*4);
    vals[i*4+0]=v.x; vals[i*4+1]=v.y; vals[i*4+2]=v.z; vals[i*4+3]=v.w;
    s += v.x+v.y+v.z+v.w;
    ss += v.x*v.x + v.y*v.y + v.z*v.z + v.w*v.w;
  }
  #pragma unroll
  for (int d = 1; d < 64; d <<= 1){ s += __shfl_xor(s, d); ss += __shfl_xor(ss, d); }
  __shared__ float red[8];
  if ((tid & 63) == 0){ red[tid>>6] = s; red[4 + (tid>>6)] = ss; }
  __syncthreads();
  s  = red[0]+red[1]+red[2]+red[3];
  ss = red[4]+red[5]+red[6]+red[7];
  float mu = s * (1.0f/HIDDEN);
  float var = ss * (1.0f/HIDDEN) - mu*mu;
  float rs = rsqrtf(var + LN_EPS);
  #pragma unroll
  for (int i = 0; i < 3; i++){
    int col = i*1024 + tid*4;
    u16x4 o;
    #pragma unroll
    for (int j = 0; j < 4; j++){
      float nv = (vals[i*4+j] - mu) * rs;
      float outv = nv * (1.0f + emb[HIDDEN + col + j]) + emb[col + j];
      o[j] = f2us(outv);
    }
    *reinterpret_cast<u16x4*>(nx + (size_t)row*HIDDEN + col) = o;
  }
}

// ------------------------------------------- W[K][N] f32 -> Wt[noff+n][k] bf16
__global__ __launch_bounds__(256)
void transpose_w(const float* __restrict__ W, u16* __restrict__ Wt,
                 int K, int N, int ldt, int noff)
{
  __shared__ float t[64][65];
  const int tid = threadIdx.x;
  const int kb = blockIdx.y * 64, nb = blockIdx.x * 64;
  #pragma unroll
  for (int i = 0; i < 4; i++){
    int row = (tid >> 4) + i*16;
    int c4  = (tid & 15) * 4;
    float4 v = *reinterpret_cast<const float4*>(W + (size_t)(kb+row)*N + nb + c4);
    t[row][c4] = v.x; t[row][c4+1] = v.y; t[row][c4+2] = v.z; t[row][c4+3] = v.w;
  }
  __syncthreads();
  int n  = tid >> 2;
  int kc = (tid & 3) * 16;
  u16 tmp[16];
  #pragma unroll
  for (int j = 0; j < 16; j++) tmp[j] = f2us(t[kc+j][n]);
  u16* dst = Wt + (size_t)(noff + nb + n)*ldt + kb + kc;
  *reinterpret_cast<i32x4*>(dst)     = *reinterpret_cast<const i32x4*>(tmp);
  *reinterpret_cast<i32x4*>(dst + 8) = *reinterpret_cast<const i32x4*>(tmp + 8);
}

// ------------------------------------------------------------- m97-style GEMM
// C[M x N] = A[M x K](bf16, lda) * Bt[N x K](bf16, ldb)^T
// EPI 0: qkv   -> bf16 out, bias selected from b0/b1/b2 by col/3072
// EPI 1: mlp   -> bf16 gelu(out+b0), written at col offset ooff
// EPI 2: final -> f32 gate*(out+b0)+residual
template<int EPI>
__global__ __launch_bounds__(256)
void gemm_bt(const u16* __restrict__ A, int lda,
             const u16* __restrict__ Bt, int ldb,
             int K, int N,
             const float* __restrict__ b0, const float* __restrict__ b1,
             const float* __restrict__ b2,
             u16* __restrict__ outb, int ldo, int ooff,
             float* __restrict__ outf,
             const float* __restrict__ emb,
             const float* __restrict__ hs, const float* __restrict__ ehs)
{
  __shared__ __align__(16) u16 As[128*64];
  __shared__ __align__(16) u16 Bs[128*64];
  const int tid = threadIdx.x, lane = tid & 63, wid = tid >> 6;
  const int l15 = lane & 15, lhi = lane >> 4;
  const int wm = wid >> 1, wn = wid & 1;

  // bijective XCD-aware swizzle (m204)
  const int gx = gridDim.x;
  const int nwg = gx * gridDim.y;
  int orig = blockIdx.y * gx + blockIdx.x;
  int qq = nwg >> 3, rr = nwg & 7;
  int xcd = orig & 7, loc = orig >> 3;
  int wg = (xcd < rr ? xcd*(qq+1) : rr*(qq+1) + (xcd-rr)*qq) + loc;
  const int n0 = (wg % gx) * 128;
  const int m0 = (wg / gx) * 128;

  f32x4 acc[4][4];
  #pragma unroll
  for (int i = 0; i < 4; i++)
    #pragma unroll
    for (int j = 0; j < 4; j++){ f32x4 z = {0.f,0.f,0.f,0.f}; acc[i][j] = z; }

  for (int k0 = 0; k0 < K; k0 += 64){
    __syncthreads();
    // stage A tile [128 rows][64 k], XOR-swizzled source -> linear LDS
    #pragma unroll
    for (int r2 = 0; r2 < 4; r2++){
      int c = r2*256 + tid;
      int row = c >> 3, j = c & 7;
      int jg = j ^ (row & 7);
      gload16(A + (size_t)(m0+row)*lda + k0 + jg*8, As + (r2*256 + wid*64)*8);
    }
    #pragma unroll
    for (int r2 = 0; r2 < 4; r2++){
      int c = r2*256 + tid;
      int row = c >> 3, j = c & 7;
      int jg = j ^ (row & 7);
      gload16(Bt + (size_t)(n0+row)*ldb + k0 + jg*8, Bs + (r2*256 + wid*64)*8);
    }
    __syncthreads();

    s16x8 af[2][4], bf_[2][4];
    #pragma unroll
    for (int h = 0; h < 2; h++){
      #pragma unroll
      for (int mf = 0; mf < 4; mf++){
        int row = wm*64 + mf*16 + l15;
        af[h][mf] = *reinterpret_cast<const s16x8*>(As + row*64 + ((((h<<2)|lhi)) ^ (row&7))*8);
      }
      #pragma unroll
      for (int nf = 0; nf < 4; nf++){
        int row = wn*64 + nf*16 + l15;
        bf_[h][nf] = *reinterpret_cast<const s16x8*>(Bs + row*64 + ((((h<<2)|lhi)) ^ (row&7))*8);
      }
    }
    #pragma unroll
    for (int h = 0; h < 2; h++)
      #pragma unroll
      for (int mf = 0; mf < 4; mf++)
        #pragma unroll
        for (int nf = 0; nf < 4; nf++)
          acc[mf][nf] = __builtin_amdgcn_mfma_f32_16x16x32_bf16(af[h][mf], bf_[h][nf], acc[mf][nf], 0, 0, 0);
  }

  // epilogue
  #pragma unroll
  for (int mf = 0; mf < 4; mf++){
    #pragma unroll
    for (int nf = 0; nf < 4; nf++){
      #pragma unroll
      for (int r = 0; r < 4; r++){
        int row = m0 + wm*64 + mf*16 + lhi*4 + r;
        int col = n0 + wn*64 + nf*16 + l15;
        if constexpr (EPI == 0){
          const float* bp = b0; int c = col;
          if (c >= 6144){ bp = b2; c -= 6144; }
          else if (c >= 3072){ bp = b1; c -= 3072; }
          outb[(size_t)row*ldo + col] = f2us(acc[mf][nf][r] + bp[c]);
        } else if constexpr (EPI == 1){
          outb[(size_t)row*ldo + ooff + col] = f2us(gelu_tanh(acc[mf][nf][r] + b0[col]));
        } else {
          float vv = acc[mf][nf][r] + b0[col];
          float res = (row < SIMG) ? hs[(size_t)row*HIDDEN + col]
                                   : ehs[(size_t)(row-SIMG)*HIDDEN + col];
          outf[(size_t)row*HIDDEN + col] = emb[2*HIDDEN + col] * vv + res;
        }
      }
    }
  }
}

// ------------------------------------------- rmsnorm + rope on q,k (in place)
__global__ __launch_bounds__(256)
void qk_post(u16* __restrict__ qkv,
             const float* __restrict__ nqw, const float* __restrict__ nkw,
             const float* __restrict__ fc)
{
  int rid = blockIdx.x*4 + (threadIdx.x >> 6);
  int lane = threadIdx.x & 63;
  int isK = rid >= NTOK*HEADS;
  int r = isK ? rid - NTOK*HEADS : rid;
  int token = r / HEADS, head = r % HEADS;
  u16* p = qkv + (size_t)token*QKVD + (isK ? HIDDEN : 0) + head*HD + lane*2;
  unsigned int u = *reinterpret_cast<unsigned int*>(p);
  float v0 = us2f((u16)(u & 0xffff));
  float v1 = us2f((u16)(u >> 16));
  float ss = v0*v0 + v1*v1;
  #pragma unroll
  for (int d = 1; d < 64; d <<= 1) ss += __shfl_xor(ss, d);
  float rs = rsqrtf(ss * (1.0f/HD) + LN_EPS);
  const float* wv = isK ? nkw : nqw;
  v0 *= rs * wv[lane*2];
  v1 *= rs * wv[lane*2+1];
  if (token < SIMG){
    const float* f = fc + (size_t)token*(2*HD);
    float c0 = f[lane*2],      c1 = f[lane*2+1];
    float s0 = f[HD + lane*2], s1 = f[HD + lane*2+1];
    float o0 = v0*c0 - v1*s0;
    float o1 = v1*c1 + v0*s1;
    v0 = o0; v1 = o1;
  }
  unsigned int uo = (unsigned int)f2us(v0) | ((unsigned int)f2us(v1) << 16);
  *reinterpret_cast<unsigned int*>(p) = uo;
}

// ------------------------------------------------------------ flash attention
__global__ __launch_bounds__(256)
void attn_kernel(const u16* __restrict__ qkv, u16* __restrict__ hcat)
{
  __shared__ __align__(16) u16 Qs[64][136];
  __shared__ __align__(16) u16 Ks[64][136];
  __shared__ __align__(16) u16 Vt[128][72];
  __shared__ __align__(16) u16 Ps[64][72];

  const int tid = threadIdx.x, lane = tid & 63, w = tid >> 6;
  const int head = blockIdx.y, qb = blockIdx.x;
  const int l15 = lane & 15, lhi = lane >> 4;
  const int q0 = qb * 64;
  const float scale = 0.08838834764831845f;

  #pragma unroll
  for (int i = 0; i < 4; i++){
    int c = tid + 256*i;
    int row = c >> 4, d0 = (c & 15) * 8;
    i32x4 vv = *reinterpret_cast<const i32x4*>(qkv + (size_t)(q0+row)*QKVD + head*HD + d0);
    *reinterpret_cast<i32x4*>(&Qs[row][d0]) = vv;
  }

  f32x4 O[8];
  #pragma unroll
  for (int i = 0; i < 8; i++){ f32x4 z = {0.f,0.f,0.f,0.f}; O[i] = z; }
  float mrow[4], lrow[4];
  #pragma unroll
  for (int r = 0; r < 4; r++){ mrow[r] = -1e30f; lrow[r] = 0.f; }

  for (int kv0 = 0; kv0 < NTOK; kv0 += 64){
    #pragma unroll
    for (int i = 0; i < 4; i++){
      int c = tid + 256*i;
      int row = c >> 4, d0 = (c & 15) * 8;
      i32x4 vv = *reinterpret_cast<const i32x4*>(qkv + (size_t)(kv0+row)*QKVD + HIDDEN + head*HD + d0);
      *reinterpret_cast<i32x4*>(&Ks[row][d0]) = vv;
    }
    #pragma unroll
    for (int i = 0; i < 4; i++){
      int c = tid + 256*i;
      int kvr = c >> 4, d0 = (c & 15) * 8;
      i32x4 vv = *reinterpret_cast<const i32x4*>(qkv + (size_t)(kv0+kvr)*QKVD + 2*HIDDEN + head*HD + d0);
      const u16* pv = reinterpret_cast<const u16*>(&vv);
      #pragma unroll
      for (int j = 0; j < 8; j++){
        int d = d0 + j;
        int col = (((kvr>>3) ^ ((d>>3)&7)) << 3) | (kvr & 7);
        Vt[d][col] = pv[j];
      }
    }
    __syncthreads();

    f32x4 S[4];
    #pragma unroll
    for (int nf = 0; nf < 4; nf++){ f32x4 z = {0.f,0.f,0.f,0.f}; S[nf] = z; }
    #pragma unroll
    for (int ks = 0; ks < 4; ks++){
      s16x8 a = *reinterpret_cast<const s16x8*>(&Qs[w*16 + l15][ks*32 + lhi*8]);
      #pragma unroll
      for (int nf = 0; nf < 4; nf++){
        s16x8 b = *reinterpret_cast<const s16x8*>(&Ks[nf*16 + l15][ks*32 + lhi*8]);
        S[nf] = __builtin_amdgcn_mfma_f32_16x16x32_bf16(a, b, S[nf], 0, 0, 0);
      }
    }
    #pragma unroll
    for (int nf = 0; nf < 4; nf++)
      #pragma unroll
      for (int r = 0; r < 4; r++) S[nf][r] *= scale;

    float fsc[4];
    #pragma unroll
    for (int r = 0; r < 4; r++){
      float mx = -1e30f;
      #pragma unroll
      for (int nf = 0; nf < 4; nf++) mx = fmaxf(mx, S[nf][r]);
      #pragma unroll
      for (int d = 1; d < 16; d <<= 1) mx = fmaxf(mx, __shfl_xor(mx, d));
      float mn = fmaxf(mrow[r], mx);
      float f = __expf(mrow[r] - mn);
      mrow[r] = mn; fsc[r] = f;
      float lsum = 0.f;
      int prow = w*16 + lhi*4 + r;
      #pragma unroll
      for (int nf = 0; nf < 4; nf++){
        float pvl = __expf(S[nf][r] - mn);
        lsum += pvl;
        int pcol = nf*16 + l15;
        int col = (((pcol>>3) ^ (prow&7)) << 3) | (pcol & 7);
        Ps[prow][col] = f2us(pvl);
      }
      #pragma unroll
      for (int d = 1; d < 16; d <<= 1) lsum += __shfl_xor(lsum, d);
      lrow[r] = lrow[r]*f + lsum;
    }
    #pragma unroll
    for (int nf = 0; nf < 8; nf++)
      #pragma unroll
      for (int r = 0; r < 4; r++) O[nf][r] *= fsc[r];
    __syncthreads();

    #pragma unroll
    for (int ks = 0; ks < 2; ks++){
      int prow = w*16 + l15;
      int cb = ((ks*4 + lhi) ^ (prow & 7)) << 3;
      s16x8 a = *reinterpret_cast<const s16x8*>(&Ps[prow][cb]);
      #pragma unroll
      for (int nf = 0; nf < 8; nf++){
        int d = nf*16 + l15;
        int vb = ((ks*4 + lhi) ^ ((d>>3)&7)) << 3;
        s16x8 b = *reinterpret_cast<const s16x8*>(&Vt[d][vb]);
        O[nf] = __builtin_amdgcn_mfma_f32_16x16x32_bf16(a, b, O[nf], 0, 0, 0);
      }
    }
    __syncthreads();
  }

  #pragma unroll
  for (int nf = 0; nf < 8; nf++){
    #pragma unroll
    for (int r = 0; r < 4; r++){
      int row = q0 + w*16 + lhi*4 + r;
      int col = head*HD + nf*16 + l15;
      hcat[(size_t)row*CATD + col] = f2us(O[nf][r] / lrow[r]);
    }
  }
}

// ---------------------------------------------------------------------- host
extern "C" void kernel_launch(void* const* d_in, const int* in_sizes, int n_in,
                              void* d_out, int out_size, void* d_ws, size_t ws_size,
                              hipStream_t stream)
{
  const float* hs    = (const float*)d_in[0];
  const float* ehs   = (const float*)d_in[1];
  const float* temb  = (const float*)d_in[2];
  const float* fc    = (const float*)d_in[3];
  const float* wnorm = (const float*)d_in[4];
  const float* bnorm = (const float*)d_in[5];
  const float* wq    = (const float*)d_in[6];
  const float* bq    = (const float*)d_in[7];
  const float* wk    = (const float*)d_in[8];
  const float* bk    = (const float*)d_in[9];
  const float* wv    = (const float*)d_in[10];
  const float* bv    = (const float*)d_in[11];
  const float* nqw   = (const float*)d_in[12];
  const float* nkw   = (const float*)d_in[13];
  const float* wmlp  = (const float*)d_in[14];
  const float* bmlp  = (const float*)d_in[15];
  const float* wout  = (const float*)d_in[16];
  const float* bout  = (const float*)d_in[17];
  float* outp = (float*)d_out;

  char* ws = (char*)d_ws;
  float* emb  = (float*)ws;                               // 36864 B
  float* part = (float*)(ws + 36864);                     // 294912 B
  u16* nx   = (u16*)(ws + 36864 + 294912);
  u16* qkv  = nx  + (size_t)NTOK*HIDDEN;
  u16* hcat = qkv + (size_t)NTOK*QKVD;
  u16* Wt   = hcat + (size_t)NTOK*CATD;                   // max 3072*15360 u16

  emb_partial<<<dim3(36,8), 256, 0, stream>>>(temb, wnorm, part);
  emb_reduce<<<36, 256, 0, stream>>>(part, bnorm, emb);
  ln_mod<<<NTOK, 256, 0, stream>>>(hs, ehs, emb, nx);

  // fused QKV: Wt[9216][3072]
  transpose_w<<<dim3(48,48), 256, 0, stream>>>(wq, Wt, HIDDEN, HIDDEN, HIDDEN, 0);
  transpose_w<<<dim3(48,48), 256, 0, stream>>>(wk, Wt, HIDDEN, HIDDEN, HIDDEN, HIDDEN);
  transpose_w<<<dim3(48,48), 256, 0, stream>>>(wv, Wt, HIDDEN, HIDDEN, HIDDEN, 2*HIDDEN);
  gemm_bt<0><<<dim3(QKVD/128, NTOK/128), 256, 0, stream>>>(
      nx, HIDDEN, Wt, HIDDEN, HIDDEN, QKVD,
      bq, bk, bv, qkv, QKVD, 0, nullptr, nullptr, nullptr, nullptr);

  qk_post<<<(2*NTOK*HEADS)/4, 256, 0, stream>>>(qkv, nqw, nkw, fc);

  // MLP: Wt[12288][3072]
  transpose_w<<<dim3(192,48), 256, 0, stream>>>(wmlp, Wt, HIDDEN, MLPD, HIDDEN, 0);
  gemm_bt<1><<<dim3(MLPD/128, NTOK/128), 256, 0, stream>>>(
      nx, HIDDEN, Wt, HIDDEN, HIDDEN, MLPD,
      bmlp, nullptr, nullptr, hcat, CATD, HIDDEN, nullptr, nullptr, nullptr, nullptr);

  attn_kernel<<<dim3(NTOK/64, HEADS), 256, 0, stream>>>(qkv, hcat);

  // out-proj: Wt[3072][15360]
  transpose_w<<<dim3(48,240), 256, 0, stream>>>(wout, Wt, CATD, HIDDEN, CATD, 0);
  gemm_bt<2><<<dim3(HIDDEN/128, NTOK/128), 256, 0, stream>>>(
      hcat, CATD, Wt, CATD, CATD, HIDDEN,
      bout, nullptr, nullptr, nullptr, 0, 0, outp, emb, hs, ehs);
}

// Round 3
// 1003.869 us; speedup vs baseline: 1.7918x; 1.2694x over previous
//
#include <hip/hip_runtime.h>
#include <hip/hip_bf16.h>

typedef unsigned short u16;
typedef short s16x8 __attribute__((ext_vector_type(8)));
typedef float f32x4 __attribute__((ext_vector_type(4)));
typedef int   i32x4 __attribute__((ext_vector_type(4)));
typedef u16   u16x4 __attribute__((ext_vector_type(4)));

#define HEADS  24
#define HD     128
#define HIDDEN 3072
#define MLPD   12288
#define NTOK   2304
#define SIMG   2048
#define NEMB   9216
#define CATD   15360   // HIDDEN + MLPD
#define QKVD   9216    // 3*HIDDEN
#define FUSEN  21504   // QKVD + MLPD
#define LN_EPS 1e-6f
#define MB     9       // 2304/256 M-blocks

__device__ __forceinline__ u16 f2us(float f){
  __hip_bfloat16 h = __float2bfloat16(f);
  return *reinterpret_cast<u16*>(&h);
}
__device__ __forceinline__ float us2f(u16 u){
  __hip_bfloat16 h;
  *reinterpret_cast<u16*>(&h) = u;
  return __bfloat162float(h);
}
__device__ __forceinline__ float gelu_tanh(float x){
  float y = 0.7978845608028654f*(x + 0.044715f*x*x*x);
  y = fminf(fmaxf(y, -12.f), 12.f);
  float e = __expf(-2.f*y);
  float t = (1.f - e) / (1.f + e);
  return 0.5f*x*(1.0f + t);
}
__device__ __forceinline__ void gload16(const u16* g, u16* l){
  __builtin_amdgcn_global_load_lds(
      (const __attribute__((address_space(1))) void*)g,
      (__attribute__((address_space(3))) void*)l, 16, 0, 0);
}
#define BAR() do{ asm volatile("":::"memory"); __builtin_amdgcn_s_barrier(); asm volatile("":::"memory"); }while(0)
#define WAITLGKM() do{ asm volatile("s_waitcnt lgkmcnt(0)":::"memory"); __builtin_amdgcn_sched_barrier(0); }while(0)
#define VMC8() asm volatile("s_waitcnt vmcnt(8)":::"memory")
#define VMC0() asm volatile("s_waitcnt vmcnt(0)":::"memory")

// ---------------------------------------------------------------- emb kernels
__global__ __launch_bounds__(256)
void emb_partial(const float* __restrict__ temb, const float* __restrict__ wn,
                 float* __restrict__ partial)
{
  __shared__ float ls[384];
  int tid = threadIdx.x;
  int kb = blockIdx.y * 384;
  for (int i = tid; i < 384; i += 256){
    float t = temb[kb + i];
    ls[i] = t / (1.0f + __expf(-t));
  }
  __syncthreads();
  int j = blockIdx.x*256 + tid;
  const float* wp = wn + (size_t)kb*NEMB + j;
  float acc = 0.f;
  #pragma unroll 8
  for (int i = 0; i < 384; i++){ acc = fmaf(ls[i], wp[0], acc); wp += NEMB; }
  partial[blockIdx.y*NEMB + j] = acc;
}

__global__ __launch_bounds__(256)
void emb_reduce(const float* __restrict__ partial, const float* __restrict__ bn,
                float* __restrict__ emb)
{
  int j = blockIdx.x*256 + threadIdx.x;
  float s = bn[j];
  #pragma unroll
  for (int r = 0; r < 8; r++) s += partial[r*NEMB + j];
  emb[j] = s;
}

// ------------------------------------------------- layernorm + modulate (bf16)
__global__ __launch_bounds__(256)
void ln_mod(const float* __restrict__ hs, const float* __restrict__ ehs,
            const float* __restrict__ emb, u16* __restrict__ nx)
{
  int row = blockIdx.x;
  const float* x = (row < SIMG) ? hs + (size_t)row*HIDDEN
                                : ehs + (size_t)(row - SIMG)*HIDDEN;
  int tid = threadIdx.x;
  float vals[12];
  float s = 0.f, ss = 0.f;
  #pragma unroll
  for (int i = 0; i < 3; i++){
    float4 v = *reinterpret_cast<const float4*>(x + i*1024 + tid*4);
    vals[i*4+0]=v.x; vals[i*4+1]=v.y; vals[i*4+2]=v.z; vals[i*4+3]=v.w;
    s += v.x+v.y+v.z+v.w;
    ss += v.x*v.x + v.y*v.y + v.z*v.z + v.w*v.w;
  }
  #pragma unroll
  for (int d = 1; d < 64; d <<= 1){ s += __shfl_xor(s, d); ss += __shfl_xor(ss, d); }
  __shared__ float red[8];
  if ((tid & 63) == 0){ red[tid>>6] = s; red[4 + (tid>>6)] = ss; }
  __syncthreads();
  s  = red[0]+red[1]+red[2]+red[3];
  ss = red[4]+red[5]+red[6]+red[7];
  float mu = s * (1.0f/HIDDEN);
  float var = ss * (1.0f/HIDDEN) - mu*mu;
  float rs = rsqrtf(var + LN_EPS);
  #pragma unroll
  for (int i = 0; i < 3; i++){
    int col = i*1024 + tid*4;
    u16x4 o;
    #pragma unroll
    for (int j = 0; j < 4; j++){
      float nv = (vals[i*4+j] - mu) * rs;
      float outv = nv * (1.0f + emb[HIDDEN + col + j]) + emb[col + j];
      o[j] = f2us(outv);
    }
    *reinterpret_cast<u16x4*>(nx + (size_t)row*HIDDEN + col) = o;
  }
}

// ------------------------------------------- W[K][N] f32 -> Wt[noff+n][k] bf16
__global__ __launch_bounds__(256)
void transpose_w(const float* __restrict__ W, u16* __restrict__ Wt,
                 int K, int N, int ldt, int noff)
{
  __shared__ float t[64][65];
  const int tid = threadIdx.x;
  const int kb = blockIdx.y * 64, nb = blockIdx.x * 64;
  #pragma unroll
  for (int i = 0; i < 4; i++){
    int row = (tid >> 4) + i*16;
    int c4  = (tid & 15) * 4;
    float4 v = *reinterpret_cast<const float4*>(W + (size_t)(kb+row)*N + nb + c4);
    t[row][c4] = v.x; t[row][c4+1] = v.y; t[row][c4+2] = v.z; t[row][c4+3] = v.w;
  }
  __syncthreads();
  int n  = tid >> 2;
  int kc = (tid & 3) * 16;
  u16 tmp[16];
  #pragma unroll
  for (int j = 0; j < 16; j++) tmp[j] = f2us(t[kc+j][n]);
  u16* dst = Wt + (size_t)(noff + nb + n)*ldt + kb + kc;
  *reinterpret_cast<i32x4*>(dst)     = *reinterpret_cast<const i32x4*>(tmp);
  *reinterpret_cast<i32x4*>(dst + 8) = *reinterpret_cast<const i32x4*>(tmp + 8);
}

// --------------------------------------------------------- 8-phase 256² GEMM
// C[2304 x N] = A[2304 x K] * Bt[N x K]^T, both bf16.
// LDS: 8 quarter-regions of 16KB: A(p,h) at (p*2+h)*8192 elems,
//      B(p,h) at 32768 + (p*2+h)*8192 elems. Region = [128 rows][64 elems],
//      packing two logical rows (2r, 2r+1) per LDS row, 16B granules
//      XOR-swizzled with (r&7).
// EPI 0: fused QKV+MLP epilogue. EPI 1: f32 partial (split-K via blockIdx.z).
template<int EPI>
__global__ __launch_bounds__(512, 2)
void gemm8(const u16* __restrict__ A_, int lda,
           const u16* __restrict__ Bt_, int ldb,
           int K, int N, int kspl,
           const float* __restrict__ b0, const float* __restrict__ b1,
           const float* __restrict__ b2, const float* __restrict__ b3,
           u16* __restrict__ qkvo, u16* __restrict__ hcat,
           float* __restrict__ outf)
{
  extern __shared__ __align__(16) u16 lds[];   // 65536 u16 = 128 KiB
  const int tid = threadIdx.x, lane = tid & 63, wid = tid >> 6;
  const int l15 = lane & 15, lhi = lane >> 4;
  const int wm = wid >> 2, wn = wid & 3;
  const int NK = K / 64;

  const u16* Ag = A_  + (size_t)blockIdx.z * kspl;
  const u16* Bg = Bt_ + (size_t)blockIdx.z * kspl;

  // bijective XCD-aware swizzle (m204), column-major block order (share B-panels)
  const int nwg = gridDim.x;
  int orig = blockIdx.x;
  int qq = nwg >> 3, rr = nwg & 7;
  int xcd = orig & 7, loc = orig >> 3;
  int wg = (xcd < rr ? xcd*(qq+1) : rr*(qq+1) + (xcd-rr)*qq) + loc;
  const int m0 = (wg % MB) * 256;
  const int n0 = (wg / MB) * 256;

  // per-thread staging offsets (2 issues per quarter-region)
  size_t offA[2], offB[2];
  int ldsq[2];
  #pragma unroll
  for (int q = 0; q < 2; q++){
    int Lb = q*8192 + tid*16;
    int r  = Lb >> 7;
    int gp = (Lb >> 4) & 7;
    int g  = gp ^ (r & 7);
    int row = 2*r + (g >> 2);
    int ke  = (g & 3) * 8;
    offA[q] = (size_t)(m0 + row)*lda + ke;
    offB[q] = (size_t)(n0 + row)*ldb + ke;
    ldsq[q] = q*4096 + tid*8;   // elem offset within region
  }

  f32x4 acc[8][4];
  #pragma unroll
  for (int i = 0; i < 8; i++)
    #pragma unroll
    for (int j = 0; j < 4; j++){ f32x4 z = {0.f,0.f,0.f,0.f}; acc[i][j] = z; }

  // issue one quarter-region (2 x global_load_lds per wave)
  #define ISSUE_A(JJ, H) do{ int jj_ = (JJ); int p2_ = jj_ & 1;                 \
      int jc_ = jj_ > NK-1 ? NK-1 : jj_;                                        \
      size_t kk_ = (size_t)jc_*64 + (H)*32;                                     \
      u16* lb_ = lds + (p2_*2 + (H))*8192;                                      \
      gload16(Ag + offA[0] + kk_, lb_ + ldsq[0]);                               \
      gload16(Ag + offA[1] + kk_, lb_ + ldsq[1]); }while(0)
  #define ISSUE_B(JJ, H) do{ int jj_ = (JJ); int p2_ = jj_ & 1;                 \
      int jc_ = jj_ > NK-1 ? NK-1 : jj_;                                        \
      size_t kk_ = (size_t)jc_*64 + (H)*32;                                     \
      u16* lb_ = lds + 32768 + (p2_*2 + (H))*8192;                              \
      gload16(Bg + offB[0] + kk_, lb_ + ldsq[0]);                               \
      gload16(Bg + offB[1] + kk_, lb_ + ldsq[1]); }while(0)

  #define LDSREAD(BASE, R) (*reinterpret_cast<const s16x8*>(                    \
      lds + (BASE) + ((R)>>1)*64 + (((((R)&1)<<2)|lhi) ^ (((R)>>1)&7))*8 ))

  #define MFMA16(C) do{                                                          \
    _Pragma("unroll") for (int mf=0; mf<4; mf++)                                 \
      _Pragma("unroll") for (int nf=0; nf<4; nf++)                               \
        acc[(C)*4+mf][nf] = __builtin_amdgcn_mfma_f32_16x16x32_bf16(             \
            af[mf], bf[nf], acc[(C)*4+mf][nf], 0, 0, 0); }while(0)

  // prologue: A_k0(0) B_k0(0) A_k1(0) B_k1(0) A_k0(1) B_k0(1)  (12 loads)
  ISSUE_A(0,0); ISSUE_B(0,0); ISSUE_A(0,1); ISSUE_B(0,1); ISSUE_A(1,0); ISSUE_B(1,0);
  VMC8();
  BAR();

  for (int j = 0; j < NK; j++){
    const int p = j & 1;
    const int bA0 = (p*2+0)*8192, bA1 = (p*2+1)*8192;
    const int bB0 = 32768 + (p*2+0)*8192, bB1 = 32768 + (p*2+1)*8192;
    s16x8 af[4], bf[4];

    // phase 1: C-half0 x k0 ; issue A(j+1, k1)
    #pragma unroll
    for (int mf = 0; mf < 4; mf++) af[mf] = LDSREAD(bA0, wm*128 + mf*16 + l15);
    #pragma unroll
    for (int nf = 0; nf < 4; nf++) bf[nf] = LDSREAD(bB0, wn*64 + nf*16 + l15);
    ISSUE_A(j+1, 1);
    BAR();
    WAITLGKM();
    __builtin_amdgcn_s_setprio(1);
    MFMA16(0);
    __builtin_amdgcn_s_setprio(0);
    BAR();

    // phase 2: C-half1 x k0 (reuse bf) ; issue B(j+1, k1) ; vmcnt checkpoint
    #pragma unroll
    for (int mf = 0; mf < 4; mf++) af[mf] = LDSREAD(bA0, wm*128 + 64 + mf*16 + l15);
    ISSUE_B(j+1, 1);
    BAR();
    WAITLGKM();
    __builtin_amdgcn_s_setprio(1);
    MFMA16(1);
    __builtin_amdgcn_s_setprio(0);
    VMC8();
    BAR();

    // phase 3: C-half0 x k1 ; issue A(j+2, k0)
    #pragma unroll
    for (int mf = 0; mf < 4; mf++) af[mf] = LDSREAD(bA1, wm*128 + mf*16 + l15);
    #pragma unroll
    for (int nf = 0; nf < 4; nf++) bf[nf] = LDSREAD(bB1, wn*64 + nf*16 + l15);
    ISSUE_A(j+2, 0);
    BAR();
    WAITLGKM();
    __builtin_amdgcn_s_setprio(1);
    MFMA16(0);
    __builtin_amdgcn_s_setprio(0);
    BAR();

    // phase 4: C-half1 x k1 ; issue B(j+2, k0) ; vmcnt checkpoint
    #pragma unroll
    for (int mf = 0; mf < 4; mf++) af[mf] = LDSREAD(bA1, wm*128 + 64 + mf*16 + l15);
    ISSUE_B(j+2, 0);
    BAR();
    WAITLGKM();
    __builtin_amdgcn_s_setprio(1);
    MFMA16(1);
    __builtin_amdgcn_s_setprio(0);
    VMC8();
    BAR();
  }
  VMC0();   // drain before LDS dealloc / epilogue

  // epilogue
  #pragma unroll
  for (int a = 0; a < 8; a++){
    #pragma unroll
    for (int nf = 0; nf < 4; nf++){
      int col = n0 + wn*64 + nf*16 + l15;
      #pragma unroll
      for (int r = 0; r < 4; r++){
        int row = m0 + wm*128 + a*16 + lhi*4 + r;
        float v = acc[a][nf][r];
        if constexpr (EPI == 0){
          if (col < QKVD){
            const float* bp = b0; int c = col;
            if (c >= 6144){ bp = b2; c -= 6144; }
            else if (c >= 3072){ bp = b1; c -= 3072; }
            qkvo[(size_t)row*QKVD + col] = f2us(v + bp[c]);
          } else {
            int c2 = col - QKVD;
            hcat[(size_t)row*CATD + HIDDEN + c2] = f2us(gelu_tanh(v + b3[c2]));
          }
        } else {
          outf[(size_t)blockIdx.z*NTOK*HIDDEN + (size_t)row*HIDDEN + col] = v;
        }
      }
    }
  }
  #undef ISSUE_A
  #undef ISSUE_B
  #undef LDSREAD
  #undef MFMA16
}

// ------------------------------------- split-K reduce + gate/residual epilogue
__global__ __launch_bounds__(256)
void reduce_out(const float* __restrict__ part, const float* __restrict__ bout,
                const float* __restrict__ emb,
                const float* __restrict__ hs, const float* __restrict__ ehs,
                float* __restrict__ outp)
{
  int row = blockIdx.x;
  const float* res = (row < SIMG) ? hs + (size_t)row*HIDDEN
                                  : ehs + (size_t)(row - SIMG)*HIDDEN;
  #pragma unroll
  for (int i = 0; i < 3; i++){
    int col = i*1024 + threadIdx.x*4;
    float4 a = *reinterpret_cast<const float4*>(part + (size_t)row*HIDDEN + col);
    float4 b = *reinterpret_cast<const float4*>(part + (size_t)NTOK*HIDDEN + (size_t)row*HIDDEN + col);
    float4 rr = *reinterpret_cast<const float4*>(res + col);
    float4 bb = *reinterpret_cast<const float4*>(bout + col);
    float4 gg = *reinterpret_cast<const float4*>(emb + 2*HIDDEN + col);
    float4 o;
    o.x = gg.x*(a.x+b.x+bb.x) + rr.x;
    o.y = gg.y*(a.y+b.y+bb.y) + rr.y;
    o.z = gg.z*(a.z+b.z+bb.z) + rr.z;
    o.w = gg.w*(a.w+b.w+bb.w) + rr.w;
    *reinterpret_cast<float4*>(outp + (size_t)row*HIDDEN + col) = o;
  }
}

// ------------------------------------------- rmsnorm + rope on q,k (in place)
__global__ __launch_bounds__(256)
void qk_post(u16* __restrict__ qkv,
             const float* __restrict__ nqw, const float* __restrict__ nkw,
             const float* __restrict__ fc)
{
  int rid = blockIdx.x*4 + (threadIdx.x >> 6);
  int lane = threadIdx.x & 63;
  int isK = rid >= NTOK*HEADS;
  int r = isK ? rid - NTOK*HEADS : rid;
  int token = r / HEADS, head = r % HEADS;
  u16* p = qkv + (size_t)token*QKVD + (isK ? HIDDEN : 0) + head*HD + lane*2;
  unsigned int u = *reinterpret_cast<unsigned int*>(p);
  float v0 = us2f((u16)(u & 0xffff));
  float v1 = us2f((u16)(u >> 16));
  float ss = v0*v0 + v1*v1;
  #pragma unroll
  for (int d = 1; d < 64; d <<= 1) ss += __shfl_xor(ss, d);
  float rs = rsqrtf(ss * (1.0f/HD) + LN_EPS);
  const float* wv = isK ? nkw : nqw;
  v0 *= rs * wv[lane*2];
  v1 *= rs * wv[lane*2+1];
  if (token < SIMG){
    const float* f = fc + (size_t)token*(2*HD);
    float c0 = f[lane*2],      c1 = f[lane*2+1];
    float s0 = f[HD + lane*2], s1 = f[HD + lane*2+1];
    float o0 = v0*c0 - v1*s0;
    float o1 = v1*c1 + v0*s1;
    v0 = o0; v1 = o1;
  }
  unsigned int uo = (unsigned int)f2us(v0) | ((unsigned int)f2us(v1) << 16);
  *reinterpret_cast<unsigned int*>(p) = uo;
}

// ------------------------------------------------------------ flash attention
__global__ __launch_bounds__(256)
void attn_kernel(const u16* __restrict__ qkv, u16* __restrict__ hcat)
{
  __shared__ __align__(16) u16 Qs[64][136];
  __shared__ __align__(16) u16 Ks[64][136];
  __shared__ __align__(16) u16 Vt[128][72];
  __shared__ __align__(16) u16 Ps[64][72];

  const int tid = threadIdx.x, lane = tid & 63, w = tid >> 6;
  const int head = blockIdx.y, qb = blockIdx.x;
  const int l15 = lane & 15, lhi = lane >> 4;
  const int q0 = qb * 64;
  const float scale = 0.08838834764831845f;

  #pragma unroll
  for (int i = 0; i < 4; i++){
    int c = tid + 256*i;
    int row = c >> 4, d0 = (c & 15) * 8;
    i32x4 vv = *reinterpret_cast<const i32x4*>(qkv + (size_t)(q0+row)*QKVD + head*HD + d0);
    *reinterpret_cast<i32x4*>(&Qs[row][d0]) = vv;
  }

  f32x4 O[8];
  #pragma unroll
  for (int i = 0; i < 8; i++){ f32x4 z = {0.f,0.f,0.f,0.f}; O[i] = z; }
  float mrow[4], lrow[4];
  #pragma unroll
  for (int r = 0; r < 4; r++){ mrow[r] = -1e30f; lrow[r] = 0.f; }

  for (int kv0 = 0; kv0 < NTOK; kv0 += 64){
    #pragma unroll
    for (int i = 0; i < 4; i++){
      int c = tid + 256*i;
      int row = c >> 4, d0 = (c & 15) * 8;
      i32x4 vv = *reinterpret_cast<const i32x4*>(qkv + (size_t)(kv0+row)*QKVD + HIDDEN + head*HD + d0);
      *reinterpret_cast<i32x4*>(&Ks[row][d0]) = vv;
    }
    #pragma unroll
    for (int i = 0; i < 4; i++){
      int c = tid + 256*i;
      int kvr = c >> 4, d0 = (c & 15) * 8;
      i32x4 vv = *reinterpret_cast<const i32x4*>(qkv + (size_t)(kv0+kvr)*QKVD + 2*HIDDEN + head*HD + d0);
      const u16* pv = reinterpret_cast<const u16*>(&vv);
      #pragma unroll
      for (int j = 0; j < 8; j++){
        int d = d0 + j;
        int col = (((kvr>>3) ^ ((d>>3)&7)) << 3) | (kvr & 7);
        Vt[d][col] = pv[j];
      }
    }
    __syncthreads();

    f32x4 S[4];
    #pragma unroll
    for (int nf = 0; nf < 4; nf++){ f32x4 z = {0.f,0.f,0.f,0.f}; S[nf] = z; }
    #pragma unroll
    for (int ks = 0; ks < 4; ks++){
      s16x8 a = *reinterpret_cast<const s16x8*>(&Qs[w*16 + l15][ks*32 + lhi*8]);
      #pragma unroll
      for (int nf = 0; nf < 4; nf++){
        s16x8 b = *reinterpret_cast<const s16x8*>(&Ks[nf*16 + l15][ks*32 + lhi*8]);
        S[nf] = __builtin_amdgcn_mfma_f32_16x16x32_bf16(a, b, S[nf], 0, 0, 0);
      }
    }
    #pragma unroll
    for (int nf = 0; nf < 4; nf++)
      #pragma unroll
      for (int r = 0; r < 4; r++) S[nf][r] *= scale;

    float fsc[4];
    #pragma unroll
    for (int r = 0; r < 4; r++){
      float mx = -1e30f;
      #pragma unroll
      for (int nf = 0; nf < 4; nf++) mx = fmaxf(mx, S[nf][r]);
      #pragma unroll
      for (int d = 1; d < 16; d <<= 1) mx = fmaxf(mx, __shfl_xor(mx, d));
      float mn = fmaxf(mrow[r], mx);
      float f = __expf(mrow[r] - mn);
      mrow[r] = mn; fsc[r] = f;
      float lsum = 0.f;
      int prow = w*16 + lhi*4 + r;
      #pragma unroll
      for (int nf = 0; nf < 4; nf++){
        float pvl = __expf(S[nf][r] - mn);
        lsum += pvl;
        int pcol = nf*16 + l15;
        int col = (((pcol>>3) ^ (prow&7)) << 3) | (pcol & 7);
        Ps[prow][col] = f2us(pvl);
      }
      #pragma unroll
      for (int d = 1; d < 16; d <<= 1) lsum += __shfl_xor(lsum, d);
      lrow[r] = lrow[r]*f + lsum;
    }
    #pragma unroll
    for (int nf = 0; nf < 8; nf++)
      #pragma unroll
      for (int r = 0; r < 4; r++) O[nf][r] *= fsc[r];
    __syncthreads();

    #pragma unroll
    for (int ks = 0; ks < 2; ks++){
      int prow = w*16 + l15;
      int cb = ((ks*4 + lhi) ^ (prow & 7)) << 3;
      s16x8 a = *reinterpret_cast<const s16x8*>(&Ps[prow][cb]);
      #pragma unroll
      for (int nf = 0; nf < 8; nf++){
        int d = nf*16 + l15;
        int vb = ((ks*4 + lhi) ^ ((d>>3)&7)) << 3;
        s16x8 b = *reinterpret_cast<const s16x8*>(&Vt[d][vb]);
        O[nf] = __builtin_amdgcn_mfma_f32_16x16x32_bf16(a, b, O[nf], 0, 0, 0);
      }
    }
    __syncthreads();
  }

  #pragma unroll
  for (int nf = 0; nf < 8; nf++){
    #pragma unroll
    for (int r = 0; r < 4; r++){
      int row = q0 + w*16 + lhi*4 + r;
      int col = head*HD + nf*16 + l15;
      hcat[(size_t)row*CATD + col] = f2us(O[nf][r] / lrow[r]);
    }
  }
}

// ---------------------------------------------------------------------- host
extern "C" void kernel_launch(void* const* d_in, const int* in_sizes, int n_in,
                              void* d_out, int out_size, void* d_ws, size_t ws_size,
                              hipStream_t stream)
{
  const float* hs    = (const float*)d_in[0];
  const float* ehs   = (const float*)d_in[1];
  const float* temb  = (const float*)d_in[2];
  const float* fc    = (const float*)d_in[3];
  const float* wnorm = (const float*)d_in[4];
  const float* bnorm = (const float*)d_in[5];
  const float* wq    = (const float*)d_in[6];
  const float* bq    = (const float*)d_in[7];
  const float* wk    = (const float*)d_in[8];
  const float* bk    = (const float*)d_in[9];
  const float* wv    = (const float*)d_in[10];
  const float* bv    = (const float*)d_in[11];
  const float* nqw   = (const float*)d_in[12];
  const float* nkw   = (const float*)d_in[13];
  const float* wmlp  = (const float*)d_in[14];
  const float* bmlp  = (const float*)d_in[15];
  const float* wout  = (const float*)d_in[16];
  const float* bout  = (const float*)d_in[17];
  float* outp = (float*)d_out;

  char* ws = (char*)d_ws;
  float* emb  = (float*)ws;                               // 36864 B
  float* part = (float*)(ws + 36864);                     // 294912 B
  u16* nx     = (u16*)(ws + 36864 + 294912);              // 14,155,776 B
  u16* qkv    = nx  + (size_t)NTOK*HIDDEN;                // 42,467,328 B
  u16* hcat   = qkv + (size_t)NTOK*QKVD;                  // 70,778,880 B
  u16* Wt     = hcat + (size_t)NTOK*CATD;                 // 132,120,576 B
  float* partial = (float*)nx;  // aliases nx+qkv (dead by out-proj time): 56.6MB

  hipFuncSetAttribute((const void*)gemm8<0>, hipFuncAttributeMaxDynamicSharedMemorySize, 131072);
  hipFuncSetAttribute((const void*)gemm8<1>, hipFuncAttributeMaxDynamicSharedMemorySize, 131072);

  emb_partial<<<dim3(36,8), 256, 0, stream>>>(temb, wnorm, part);
  emb_reduce<<<36, 256, 0, stream>>>(part, bnorm, emb);
  ln_mod<<<NTOK, 256, 0, stream>>>(hs, ehs, emb, nx);

  // Wt rows: [0,9216) = q|k|v ; [9216,21504) = mlp ; ldt = 3072
  transpose_w<<<dim3(48,48), 256, 0, stream>>>(wq,   Wt, HIDDEN, HIDDEN, HIDDEN, 0);
  transpose_w<<<dim3(48,48), 256, 0, stream>>>(wk,   Wt, HIDDEN, HIDDEN, HIDDEN, HIDDEN);
  transpose_w<<<dim3(48,48), 256, 0, stream>>>(wv,   Wt, HIDDEN, HIDDEN, HIDDEN, 2*HIDDEN);
  transpose_w<<<dim3(192,48), 256, 0, stream>>>(wmlp, Wt, HIDDEN, MLPD, HIDDEN, QKVD);

  // fused QKV+MLP GEMM: [2304 x 21504], K=3072
  gemm8<0><<<dim3((FUSEN/256)*MB, 1, 1), 512, 131072, stream>>>(
      nx, HIDDEN, Wt, HIDDEN, HIDDEN, FUSEN, 0,
      bq, bk, bv, bmlp, qkv, hcat, nullptr);

  // out-proj weights: Wt[3072][15360] (reuses Wt region)
  transpose_w<<<dim3(48,240), 256, 0, stream>>>(wout, Wt, CATD, HIDDEN, CATD, 0);

  qk_post<<<(2*NTOK*HEADS)/4, 256, 0, stream>>>(qkv, nqw, nkw, fc);
  attn_kernel<<<dim3(NTOK/64, HEADS), 256, 0, stream>>>(qkv, hcat);

  // out-proj: split-K=2, f32 partials
  gemm8<1><<<dim3((HIDDEN/256)*MB, 1, 2), 512, 131072, stream>>>(
      hcat, CATD, Wt, CATD, CATD/2, HIDDEN, CATD/2,
      nullptr, nullptr, nullptr, nullptr, nullptr, nullptr, partial);

  reduce_out<<<NTOK, 256, 0, stream>>>(partial, bout, emb, hs, ehs, outp);
}

// Round 4
// 980.043 us; speedup vs baseline: 1.8354x; 1.0243x over previous
//
#include <hip/hip_runtime.h>
#include <hip/hip_bf16.h>

typedef unsigned short u16;
typedef short s16x8 __attribute__((ext_vector_type(8)));
typedef float f32x4 __attribute__((ext_vector_type(4)));
typedef int   i32x4 __attribute__((ext_vector_type(4)));
typedef u16   u16x4 __attribute__((ext_vector_type(4)));

#define HEADS  24
#define HD     128
#define HIDDEN 3072
#define MLPD   12288
#define NTOK   2304
#define SIMG   2048
#define NEMB   9216
#define CATD   15360   // HIDDEN + MLPD
#define QKVD   9216    // 3*HIDDEN
#define FUSEN  21504   // QKVD + MLPD
#define LN_EPS 1e-6f
#define MB     9       // 2304/256 M-blocks

__device__ __forceinline__ u16 f2us(float f){
  __hip_bfloat16 h = __float2bfloat16(f);
  return *reinterpret_cast<u16*>(&h);
}
__device__ __forceinline__ float us2f(u16 u){
  __hip_bfloat16 h;
  *reinterpret_cast<u16*>(&h) = u;
  return __bfloat162float(h);
}
__device__ __forceinline__ float gelu_tanh(float x){
  float y = 0.7978845608028654f*(x + 0.044715f*x*x*x);
  y = fminf(fmaxf(y, -12.f), 12.f);
  float e = __expf(-2.f*y);
  float t = (1.f - e) / (1.f + e);
  return 0.5f*x*(1.0f + t);
}
__device__ __forceinline__ void gload16(const u16* g, u16* l){
  __builtin_amdgcn_global_load_lds(
      (const __attribute__((address_space(1))) void*)g,
      (__attribute__((address_space(3))) void*)l, 16, 0, 0);
}
#define BAR() do{ asm volatile("":::"memory"); __builtin_amdgcn_s_barrier(); asm volatile("":::"memory"); }while(0)
#define WAITLGKM() do{ asm volatile("s_waitcnt lgkmcnt(0)":::"memory"); __builtin_amdgcn_sched_barrier(0); }while(0)
#define VMW_(n) asm volatile("s_waitcnt vmcnt(" #n ")":::"memory")
#define VMW(n) VMW_(n)
#define VMC0() asm volatile("s_waitcnt vmcnt(0)":::"memory")

// ---------------------------------------------------------------- emb kernels
__global__ __launch_bounds__(256)
void emb_partial(const float* __restrict__ temb, const float* __restrict__ wn,
                 float* __restrict__ partial)
{
  __shared__ float ls[384];
  int tid = threadIdx.x;
  int kb = blockIdx.y * 384;
  for (int i = tid; i < 384; i += 256){
    float t = temb[kb + i];
    ls[i] = t / (1.0f + __expf(-t));
  }
  __syncthreads();
  int j = blockIdx.x*256 + tid;
  const float* wp = wn + (size_t)kb*NEMB + j;
  float acc = 0.f;
  #pragma unroll 8
  for (int i = 0; i < 384; i++){ acc = fmaf(ls[i], wp[0], acc); wp += NEMB; }
  partial[blockIdx.y*NEMB + j] = acc;
}

__global__ __launch_bounds__(256)
void emb_reduce(const float* __restrict__ partial, const float* __restrict__ bn,
                float* __restrict__ emb)
{
  int j = blockIdx.x*256 + threadIdx.x;
  float s = bn[j];
  #pragma unroll
  for (int r = 0; r < 8; r++) s += partial[r*NEMB + j];
  emb[j] = s;
}

// ------------------------------------------------- layernorm + modulate (bf16)
__global__ __launch_bounds__(256)
void ln_mod(const float* __restrict__ hs, const float* __restrict__ ehs,
            const float* __restrict__ emb, u16* __restrict__ nx)
{
  int row = blockIdx.x;
  const float* x = (row < SIMG) ? hs + (size_t)row*HIDDEN
                                : ehs + (size_t)(row - SIMG)*HIDDEN;
  int tid = threadIdx.x;
  float vals[12];
  float s = 0.f, ss = 0.f;
  #pragma unroll
  for (int i = 0; i < 3; i++){
    float4 v = *reinterpret_cast<const float4*>(x + i*1024 + tid*4);
    vals[i*4+0]=v.x; vals[i*4+1]=v.y; vals[i*4+2]=v.z; vals[i*4+3]=v.w;
    s += v.x+v.y+v.z+v.w;
    ss += v.x*v.x + v.y*v.y + v.z*v.z + v.w*v.w;
  }
  #pragma unroll
  for (int d = 1; d < 64; d <<= 1){ s += __shfl_xor(s, d); ss += __shfl_xor(ss, d); }
  __shared__ float red[8];
  if ((tid & 63) == 0){ red[tid>>6] = s; red[4 + (tid>>6)] = ss; }
  __syncthreads();
  s  = red[0]+red[1]+red[2]+red[3];
  ss = red[4]+red[5]+red[6]+red[7];
  float mu = s * (1.0f/HIDDEN);
  float var = ss * (1.0f/HIDDEN) - mu*mu;
  float rs = rsqrtf(var + LN_EPS);
  #pragma unroll
  for (int i = 0; i < 3; i++){
    int col = i*1024 + tid*4;
    u16x4 o;
    #pragma unroll
    for (int j = 0; j < 4; j++){
      float nv = (vals[i*4+j] - mu) * rs;
      float outv = nv * (1.0f + emb[HIDDEN + col + j]) + emb[col + j];
      o[j] = f2us(outv);
    }
    *reinterpret_cast<u16x4*>(nx + (size_t)row*HIDDEN + col) = o;
  }
}

// ------------------------------------------- W[K][N] f32 -> Wt[noff+n][k] bf16
__global__ __launch_bounds__(256)
void transpose_w(const float* __restrict__ W, u16* __restrict__ Wt,
                 int K, int N, int ldt, int noff)
{
  __shared__ float t[64][65];
  const int tid = threadIdx.x;
  const int kb = blockIdx.y * 64, nb = blockIdx.x * 64;
  #pragma unroll
  for (int i = 0; i < 4; i++){
    int row = (tid >> 4) + i*16;
    int c4  = (tid & 15) * 4;
    float4 v = *reinterpret_cast<const float4*>(W + (size_t)(kb+row)*N + nb + c4);
    t[row][c4] = v.x; t[row][c4+1] = v.y; t[row][c4+2] = v.z; t[row][c4+3] = v.w;
  }
  __syncthreads();
  int n  = tid >> 2;
  int kc = (tid & 3) * 16;
  u16 tmp[16];
  #pragma unroll
  for (int j = 0; j < 16; j++) tmp[j] = f2us(t[kc+j][n]);
  u16* dst = Wt + (size_t)(noff + nb + n)*ldt + kb + kc;
  *reinterpret_cast<i32x4*>(dst)     = *reinterpret_cast<const i32x4*>(tmp);
  *reinterpret_cast<i32x4*>(dst + 8) = *reinterpret_cast<const i32x4*>(tmp + 8);
}

// --------------------------------------------------------- 8-phase 256² GEMM
// C[2304 x N] = A[2304 x K] * Bt[N x K]^T, both bf16. Same quarter-region
// ledger as Round 3 (proven race-free), but: K-loop unrolled x2 so region
// bases are compile-time (ds_read offset immediates), LDS read addresses
// precomputed once per lane, global staging via 4 advancing pointers with
// immediate offsets, tail peeled with vmcnt 8->4->0 ledger (no OOB).
// EPI 0: fused QKV+MLP epilogue. EPI 1: f32 partial (split-K via blockIdx.z).
template<int EPI>
__global__ __launch_bounds__(512, 2)
void gemm8(const u16* __restrict__ A_, int lda,
           const u16* __restrict__ Bt_, int ldb,
           int K, int N, int kspl,
           const float* __restrict__ b0, const float* __restrict__ b1,
           const float* __restrict__ b2, const float* __restrict__ b3,
           u16* __restrict__ qkvo, u16* __restrict__ hcat,
           float* __restrict__ outf)
{
  extern __shared__ __align__(16) u16 lds[];   // 65536 u16 = 128 KiB
  const int tid = threadIdx.x, lane = tid & 63, wid = tid >> 6;
  const int l15 = lane & 15, lhi = lane >> 4;
  const int wm = wid >> 2, wn = wid & 3;
  const int NK = K / 64;    // must be even and >= 6

  const u16* Ag = A_  + (size_t)blockIdx.z * kspl;
  const u16* Bg = Bt_ + (size_t)blockIdx.z * kspl;

  // bijective XCD-aware swizzle (m204), column-major block order
  const int nwg = gridDim.x;
  int orig = blockIdx.x;
  int qq = nwg >> 3, rr = nwg & 7;
  int xcd = orig & 7, loc = orig >> 3;
  int wg = (xcd < rr ? xcd*(qq+1) : rr*(qq+1) + (xcd-rr)*qq) + loc;
  const int m0 = (wg % MB) * 256;
  const int n0 = (wg / MB) * 256;

  // staging global pointers (2 issues per quarter-region per wave)
  const u16 *gA0, *gA1, *gB0, *gB1;
  {
    size_t offA[2], offB[2];
    #pragma unroll
    for (int q = 0; q < 2; q++){
      int Lb = q*8192 + tid*16;          // byte offset within region
      int r  = Lb >> 7;                  // LDS row (128B rows)
      int gp = (Lb >> 4) & 7;
      int g  = gp ^ (r & 7);
      int row = 2*r + (g >> 2);
      int ke  = (g & 3) * 8;
      offA[q] = (size_t)(m0 + row)*lda + ke;
      offB[q] = (size_t)(n0 + row)*ldb + ke;
    }
    gA0 = Ag + offA[0]; gA1 = Ag + offA[1];
    gB0 = Bg + offB[0]; gB1 = Bg + offB[1];
  }
  // staging LDS destinations (elem offsets; region base added as const)
  u16* dA0 = lds + tid*8;
  u16* dA1 = lds + 4096 + tid*8;
  u16* dB0 = lds + 32768 + tid*8;
  u16* dB1 = lds + 36864 + tid*8;

  // precomputed per-lane LDS read pointers (region base folds into offset imm)
  const char* pa[8];
  const char* pb[4];
  {
    const char* LB = (const char*)lds;
    #pragma unroll
    for (int c = 0; c < 2; c++)
      #pragma unroll
      for (int mf = 0; mf < 4; mf++){
        int R = wm*128 + c*64 + mf*16 + l15;
        int off = (R>>1)*128 + (((((R&1)<<2)|lhi) ^ ((R>>1)&7))*16);
        pa[c*4+mf] = LB + off;
      }
    #pragma unroll
    for (int nf = 0; nf < 4; nf++){
      int R = wn*64 + nf*16 + l15;
      int off = (R>>1)*128 + (((((R&1)<<2)|lhi) ^ ((R>>1)&7))*16);
      pb[nf] = LB + 65536 + off;
    }
  }

  f32x4 acc[8][4];
  #pragma unroll
  for (int i = 0; i < 8; i++)
    #pragma unroll
    for (int j = 0; j < 4; j++){ f32x4 z = {0.f,0.f,0.f,0.f}; acc[i][j] = z; }

  #define LD8(P_) (*reinterpret_cast<const s16x8*>(P_))
  #define MFMA_BLK(A0_) do{                                                    \
    _Pragma("unroll") for (int mf_=0; mf_<4; mf_++)                            \
      _Pragma("unroll") for (int nf_=0; nf_<4; nf_++)                          \
        acc[(A0_)+mf_][nf_] = __builtin_amdgcn_mfma_f32_16x16x32_bf16(         \
            af[mf_], bf[nf_], acc[(A0_)+mf_][nf_], 0, 0, 0); }while(0)

  // one K-iter (4 phases). P_: parity (compile-time). DOE_: issue (j+1,k1).
  // DOL_: issue (j+2,k0). EOFF_/LOFF_: global elem offsets rel. to pointers.
  #define KBODY(P_,DOE_,DOL_,EOFF_,LOFF_,V2_,V4_) do{                          \
    constexpr int CA0 = (P_)?32768:0, CA1 = (P_)?49152:16384;                  \
    constexpr int ERE = (P_)?8192:24576, LRE = (P_)?16384:0;                   \
    s16x8 af[4], bf[4];                                                        \
    /* phase 1: C-half0 x k0 */                                                \
    _Pragma("unroll") for (int i_=0;i_<4;i_++) af[i_] = LD8(pa[i_]+CA0);       \
    _Pragma("unroll") for (int i_=0;i_<4;i_++) bf[i_] = LD8(pb[i_]+CA0);       \
    if (DOE_){ gload16(gA0+(EOFF_), dA0+ERE); gload16(gA1+(EOFF_), dA1+ERE); } \
    BAR(); WAITLGKM();                                                         \
    __builtin_amdgcn_s_setprio(1); MFMA_BLK(0); __builtin_amdgcn_s_setprio(0); \
    BAR();                                                                     \
    /* phase 2: C-half1 x k0 (reuse bf) */                                     \
    _Pragma("unroll") for (int i_=0;i_<4;i_++) af[i_] = LD8(pa[4+i_]+CA0);     \
    if (DOE_){ gload16(gB0+(EOFF_), dB0+ERE); gload16(gB1+(EOFF_), dB1+ERE); } \
    BAR(); WAITLGKM();                                                         \
    __builtin_amdgcn_s_setprio(1); MFMA_BLK(4); __builtin_amdgcn_s_setprio(0); \
    VMW(V2_); BAR();                                                           \
    /* phase 3: C-half0 x k1 */                                                \
    _Pragma("unroll") for (int i_=0;i_<4;i_++) af[i_] = LD8(pa[i_]+CA1);       \
    _Pragma("unroll") for (int i_=0;i_<4;i_++) bf[i_] = LD8(pb[i_]+CA1);       \
    if (DOL_){ gload16(gA0+(LOFF_), dA0+LRE); gload16(gA1+(LOFF_), dA1+LRE); } \
    BAR(); WAITLGKM();                                                         \
    __builtin_amdgcn_s_setprio(1); MFMA_BLK(0); __builtin_amdgcn_s_setprio(0); \
    BAR();                                                                     \
    /* phase 4: C-half1 x k1 */                                                \
    _Pragma("unroll") for (int i_=0;i_<4;i_++) af[i_] = LD8(pa[4+i_]+CA1);     \
    if (DOL_){ gload16(gB0+(LOFF_), dB0+LRE); gload16(gB1+(LOFF_), dB1+LRE); } \
    BAR(); WAITLGKM();                                                         \
    __builtin_amdgcn_s_setprio(1); MFMA_BLK(4); __builtin_amdgcn_s_setprio(0); \
    VMW(V4_); BAR();                                                           \
  }while(0)

  // prologue: A(0,0) B(0,0) A(0,1) B(0,1) A(1,0) B(1,0)  (12 loads)
  gload16(gA0,    dA0);         gload16(gA1,    dA1);
  gload16(gB0,    dB0);         gload16(gB1,    dB1);
  gload16(gA0+32, dA0+8192);    gload16(gA1+32, dA1+8192);
  gload16(gB0+32, dB0+8192);    gload16(gB1+32, dB1+8192);
  gload16(gA0+64, dA0+16384);   gload16(gA1+64, dA1+16384);
  gload16(gB0+64, dB0+16384);   gload16(gB1+64, dB1+16384);
  VMW(8);
  BAR();

  for (int jj = 0; jj + 3 < NK; jj += 2){
    KBODY(0, 1, 1,  96, 128, 8, 8);
    KBODY(1, 1, 1, 160, 192, 8, 8);
    gA0 += 128; gA1 += 128; gB0 += 128; gB1 += 128;
  }
  // tail: j = NK-2 (parity 0): issue only (NK-1,k1); vmcnt 8 then 4
  KBODY(0, 1, 0, 96, 0, 8, 4);
  // tail: j = NK-1 (parity 1): no issues; vmcnt 0 mid-iter
  KBODY(1, 0, 0, 0, 0, 0, 0);
  VMC0();

  #undef KBODY
  #undef MFMA_BLK
  #undef LD8

  // epilogue
  #pragma unroll
  for (int a = 0; a < 8; a++){
    #pragma unroll
    for (int nf = 0; nf < 4; nf++){
      int col = n0 + wn*64 + nf*16 + l15;
      #pragma unroll
      for (int r = 0; r < 4; r++){
        int row = m0 + wm*128 + a*16 + lhi*4 + r;
        float v = acc[a][nf][r];
        if constexpr (EPI == 0){
          if (col < QKVD){
            const float* bp = b0; int c = col;
            if (c >= 6144){ bp = b2; c -= 6144; }
            else if (c >= 3072){ bp = b1; c -= 3072; }
            qkvo[(size_t)row*QKVD + col] = f2us(v + bp[c]);
          } else {
            int c2 = col - QKVD;
            hcat[(size_t)row*CATD + HIDDEN + c2] = f2us(gelu_tanh(v + b3[c2]));
          }
        } else {
          outf[(size_t)blockIdx.z*NTOK*HIDDEN + (size_t)row*HIDDEN + col] = v;
        }
      }
    }
  }
}

// ------------------------------------- split-K reduce + gate/residual epilogue
__global__ __launch_bounds__(256)
void reduce_out(const float* __restrict__ part, const float* __restrict__ bout,
                const float* __restrict__ emb,
                const float* __restrict__ hs, const float* __restrict__ ehs,
                float* __restrict__ outp)
{
  int row = blockIdx.x;
  const float* res = (row < SIMG) ? hs + (size_t)row*HIDDEN
                                  : ehs + (size_t)(row - SIMG)*HIDDEN;
  #pragma unroll
  for (int i = 0; i < 3; i++){
    int col = i*1024 + threadIdx.x*4;
    float4 a = *reinterpret_cast<const float4*>(part + (size_t)row*HIDDEN + col);
    float4 b = *reinterpret_cast<const float4*>(part + (size_t)NTOK*HIDDEN + (size_t)row*HIDDEN + col);
    float4 rr = *reinterpret_cast<const float4*>(res + col);
    float4 bb = *reinterpret_cast<const float4*>(bout + col);
    float4 gg = *reinterpret_cast<const float4*>(emb + 2*HIDDEN + col);
    float4 o;
    o.x = gg.x*(a.x+b.x+bb.x) + rr.x;
    o.y = gg.y*(a.y+b.y+bb.y) + rr.y;
    o.z = gg.z*(a.z+b.z+bb.z) + rr.z;
    o.w = gg.w*(a.w+b.w+bb.w) + rr.w;
    *reinterpret_cast<float4*>(outp + (size_t)row*HIDDEN + col) = o;
  }
}

// ------------------------------------------- rmsnorm + rope on q,k (in place)
__global__ __launch_bounds__(256)
void qk_post(u16* __restrict__ qkv,
             const float* __restrict__ nqw, const float* __restrict__ nkw,
             const float* __restrict__ fc)
{
  int rid = blockIdx.x*4 + (threadIdx.x >> 6);
  int lane = threadIdx.x & 63;
  int isK = rid >= NTOK*HEADS;
  int r = isK ? rid - NTOK*HEADS : rid;
  int token = r / HEADS, head = r % HEADS;
  u16* p = qkv + (size_t)token*QKVD + (isK ? HIDDEN : 0) + head*HD + lane*2;
  unsigned int u = *reinterpret_cast<unsigned int*>(p);
  float v0 = us2f((u16)(u & 0xffff));
  float v1 = us2f((u16)(u >> 16));
  float ss = v0*v0 + v1*v1;
  #pragma unroll
  for (int d = 1; d < 64; d <<= 1) ss += __shfl_xor(ss, d);
  float rs = rsqrtf(ss * (1.0f/HD) + LN_EPS);
  const float* wv = isK ? nkw : nqw;
  v0 *= rs * wv[lane*2];
  v1 *= rs * wv[lane*2+1];
  if (token < SIMG){
    const float* f = fc + (size_t)token*(2*HD);
    float c0 = f[lane*2],      c1 = f[lane*2+1];
    float s0 = f[HD + lane*2], s1 = f[HD + lane*2+1];
    float o0 = v0*c0 - v1*s0;
    float o1 = v1*c1 + v0*s1;
    v0 = o0; v1 = o1;
  }
  unsigned int uo = (unsigned int)f2us(v0) | ((unsigned int)f2us(v1) << 16);
  *reinterpret_cast<unsigned int*>(p) = uo;
}

// ------------------------------------------------------------ flash attention
__global__ __launch_bounds__(256)
void attn_kernel(const u16* __restrict__ qkv, u16* __restrict__ hcat)
{
  __shared__ __align__(16) u16 Qs[64][136];
  __shared__ __align__(16) u16 Ks[64][136];
  __shared__ __align__(16) u16 Vt[128][72];
  __shared__ __align__(16) u16 Ps[64][72];

  const int tid = threadIdx.x, lane = tid & 63, w = tid >> 6;
  const int head = blockIdx.y, qb = blockIdx.x;
  const int l15 = lane & 15, lhi = lane >> 4;
  const int q0 = qb * 64;
  const float scale = 0.08838834764831845f;

  #pragma unroll
  for (int i = 0; i < 4; i++){
    int c = tid + 256*i;
    int row = c >> 4, d0 = (c & 15) * 8;
    i32x4 vv = *reinterpret_cast<const i32x4*>(qkv + (size_t)(q0+row)*QKVD + head*HD + d0);
    *reinterpret_cast<i32x4*>(&Qs[row][d0]) = vv;
  }

  f32x4 O[8];
  #pragma unroll
  for (int i = 0; i < 8; i++){ f32x4 z = {0.f,0.f,0.f,0.f}; O[i] = z; }
  float mrow[4], lrow[4];
  #pragma unroll
  for (int r = 0; r < 4; r++){ mrow[r] = -1e30f; lrow[r] = 0.f; }

  for (int kv0 = 0; kv0 < NTOK; kv0 += 64){
    #pragma unroll
    for (int i = 0; i < 4; i++){
      int c = tid + 256*i;
      int row = c >> 4, d0 = (c & 15) * 8;
      i32x4 vv = *reinterpret_cast<const i32x4*>(qkv + (size_t)(kv0+row)*QKVD + HIDDEN + head*HD + d0);
      *reinterpret_cast<i32x4*>(&Ks[row][d0]) = vv;
    }
    #pragma unroll
    for (int i = 0; i < 4; i++){
      int c = tid + 256*i;
      int kvr = c >> 4, d0 = (c & 15) * 8;
      i32x4 vv = *reinterpret_cast<const i32x4*>(qkv + (size_t)(kv0+kvr)*QKVD + 2*HIDDEN + head*HD + d0);
      const u16* pv = reinterpret_cast<const u16*>(&vv);
      #pragma unroll
      for (int j = 0; j < 8; j++){
        int d = d0 + j;
        int col = (((kvr>>3) ^ ((d>>3)&7)) << 3) | (kvr & 7);
        Vt[d][col] = pv[j];
      }
    }
    __syncthreads();

    f32x4 S[4];
    #pragma unroll
    for (int nf = 0; nf < 4; nf++){ f32x4 z = {0.f,0.f,0.f,0.f}; S[nf] = z; }
    #pragma unroll
    for (int ks = 0; ks < 4; ks++){
      s16x8 a = *reinterpret_cast<const s16x8*>(&Qs[w*16 + l15][ks*32 + lhi*8]);
      #pragma unroll
      for (int nf = 0; nf < 4; nf++){
        s16x8 b = *reinterpret_cast<const s16x8*>(&Ks[nf*16 + l15][ks*32 + lhi*8]);
        S[nf] = __builtin_amdgcn_mfma_f32_16x16x32_bf16(a, b, S[nf], 0, 0, 0);
      }
    }
    #pragma unroll
    for (int nf = 0; nf < 4; nf++)
      #pragma unroll
      for (int r = 0; r < 4; r++) S[nf][r] *= scale;

    float fsc[4];
    #pragma unroll
    for (int r = 0; r < 4; r++){
      float mx = -1e30f;
      #pragma unroll
      for (int nf = 0; nf < 4; nf++) mx = fmaxf(mx, S[nf][r]);
      #pragma unroll
      for (int d = 1; d < 16; d <<= 1) mx = fmaxf(mx, __shfl_xor(mx, d));
      float mn = fmaxf(mrow[r], mx);
      float f = __expf(mrow[r] - mn);
      mrow[r] = mn; fsc[r] = f;
      float lsum = 0.f;
      int prow = w*16 + lhi*4 + r;
      #pragma unroll
      for (int nf = 0; nf < 4; nf++){
        float pvl = __expf(S[nf][r] - mn);
        lsum += pvl;
        int pcol = nf*16 + l15;
        int col = (((pcol>>3) ^ (prow&7)) << 3) | (pcol & 7);
        Ps[prow][col] = f2us(pvl);
      }
      #pragma unroll
      for (int d = 1; d < 16; d <<= 1) lsum += __shfl_xor(lsum, d);
      lrow[r] = lrow[r]*f + lsum;
    }
    #pragma unroll
    for (int nf = 0; nf < 8; nf++)
      #pragma unroll
      for (int r = 0; r < 4; r++) O[nf][r] *= fsc[r];
    __syncthreads();

    #pragma unroll
    for (int ks = 0; ks < 2; ks++){
      int prow = w*16 + l15;
      int cb = ((ks*4 + lhi) ^ (prow & 7)) << 3;
      s16x8 a = *reinterpret_cast<const s16x8*>(&Ps[prow][cb]);
      #pragma unroll
      for (int nf = 0; nf < 8; nf++){
        int d = nf*16 + l15;
        int vb = ((ks*4 + lhi) ^ ((d>>3)&7)) << 3;
        s16x8 b = *reinterpret_cast<const s16x8*>(&Vt[d][vb]);
        O[nf] = __builtin_amdgcn_mfma_f32_16x16x32_bf16(a, b, O[nf], 0, 0, 0);
      }
    }
    __syncthreads();
  }

  #pragma unroll
  for (int nf = 0; nf < 8; nf++){
    #pragma unroll
    for (int r = 0; r < 4; r++){
      int row = q0 + w*16 + lhi*4 + r;
      int col = head*HD + nf*16 + l15;
      hcat[(size_t)row*CATD + col] = f2us(O[nf][r] / lrow[r]);
    }
  }
}

// ---------------------------------------------------------------------- host
extern "C" void kernel_launch(void* const* d_in, const int* in_sizes, int n_in,
                              void* d_out, int out_size, void* d_ws, size_t ws_size,
                              hipStream_t stream)
{
  const float* hs    = (const float*)d_in[0];
  const float* ehs   = (const float*)d_in[1];
  const float* temb  = (const float*)d_in[2];
  const float* fc    = (const float*)d_in[3];
  const float* wnorm = (const float*)d_in[4];
  const float* bnorm = (const float*)d_in[5];
  const float* wq    = (const float*)d_in[6];
  const float* bq    = (const float*)d_in[7];
  const float* wk    = (const float*)d_in[8];
  const float* bk    = (const float*)d_in[9];
  const float* wv    = (const float*)d_in[10];
  const float* bv    = (const float*)d_in[11];
  const float* nqw   = (const float*)d_in[12];
  const float* nkw   = (const float*)d_in[13];
  const float* wmlp  = (const float*)d_in[14];
  const float* bmlp  = (const float*)d_in[15];
  const float* wout  = (const float*)d_in[16];
  const float* bout  = (const float*)d_in[17];
  float* outp = (float*)d_out;

  char* ws = (char*)d_ws;
  float* emb  = (float*)ws;                               // 36864 B
  float* part = (float*)(ws + 36864);                     // 294912 B
  u16* nx     = (u16*)(ws + 36864 + 294912);              // 14,155,776 B
  u16* qkv    = nx  + (size_t)NTOK*HIDDEN;                // 42,467,328 B
  u16* hcat   = qkv + (size_t)NTOK*QKVD;                  // 70,778,880 B
  u16* Wt     = hcat + (size_t)NTOK*CATD;                 // 132,120,576 B
  float* partial = (float*)nx;  // aliases nx+qkv (dead by out-proj time)

  hipFuncSetAttribute((const void*)gemm8<0>, hipFuncAttributeMaxDynamicSharedMemorySize, 131072);
  hipFuncSetAttribute((const void*)gemm8<1>, hipFuncAttributeMaxDynamicSharedMemorySize, 131072);

  emb_partial<<<dim3(36,8), 256, 0, stream>>>(temb, wnorm, part);
  emb_reduce<<<36, 256, 0, stream>>>(part, bnorm, emb);
  ln_mod<<<NTOK, 256, 0, stream>>>(hs, ehs, emb, nx);

  // Wt rows: [0,9216) = q|k|v ; [9216,21504) = mlp ; ldt = 3072
  transpose_w<<<dim3(48,48), 256, 0, stream>>>(wq,   Wt, HIDDEN, HIDDEN, HIDDEN, 0);
  transpose_w<<<dim3(48,48), 256, 0, stream>>>(wk,   Wt, HIDDEN, HIDDEN, HIDDEN, HIDDEN);
  transpose_w<<<dim3(48,48), 256, 0, stream>>>(wv,   Wt, HIDDEN, HIDDEN, HIDDEN, 2*HIDDEN);
  transpose_w<<<dim3(192,48), 256, 0, stream>>>(wmlp, Wt, HIDDEN, MLPD, HIDDEN, QKVD);

  // fused QKV+MLP GEMM: [2304 x 21504], K=3072 (NK=48)
  gemm8<0><<<dim3((FUSEN/256)*MB, 1, 1), 512, 131072, stream>>>(
      nx, HIDDEN, Wt, HIDDEN, HIDDEN, FUSEN, 0,
      bq, bk, bv, bmlp, qkv, hcat, nullptr);

  // out-proj weights: Wt[3072][15360] (reuses Wt region)
  transpose_w<<<dim3(48,240), 256, 0, stream>>>(wout, Wt, CATD, HIDDEN, CATD, 0);

  qk_post<<<(2*NTOK*HEADS)/4, 256, 0, stream>>>(qkv, nqw, nkw, fc);
  attn_kernel<<<dim3(NTOK/64, HEADS), 256, 0, stream>>>(qkv, hcat);

  // out-proj: split-K=2 (NK=120 each), f32 partials
  gemm8<1><<<dim3((HIDDEN/256)*MB, 1, 2), 512, 131072, stream>>>(
      hcat, CATD, Wt, CATD, CATD/2, HIDDEN, CATD/2,
      nullptr, nullptr, nullptr, nullptr, nullptr, nullptr, partial);

  reduce_out<<<NTOK, 256, 0, stream>>>(partial, bout, emb, hs, ehs, outp);
}

// Round 5
// 979.693 us; speedup vs baseline: 1.8360x; 1.0004x over previous
//
#include <hip/hip_runtime.h>
#include <hip/hip_bf16.h>

typedef unsigned short u16;
typedef short s16x8 __attribute__((ext_vector_type(8)));
typedef float f32x4 __attribute__((ext_vector_type(4)));
typedef int   i32x4 __attribute__((ext_vector_type(4)));
typedef u16   u16x4 __attribute__((ext_vector_type(4)));

#define HEADS  24
#define HD     128
#define HIDDEN 3072
#define MLPD   12288
#define NTOK   2304
#define SIMG   2048
#define NEMB   9216
#define CATD   15360   // HIDDEN + MLPD
#define QKVD   9216    // 3*HIDDEN
#define FUSEN  21504   // QKVD + MLPD
#define LN_EPS 1e-6f
#define MB     9       // 2304/256 M-blocks

__device__ __forceinline__ u16 f2us(float f){
  __hip_bfloat16 h = __float2bfloat16(f);
  return *reinterpret_cast<u16*>(&h);
}
__device__ __forceinline__ float us2f(u16 u){
  __hip_bfloat16 h;
  *reinterpret_cast<u16*>(&h) = u;
  return __bfloat162float(h);
}
__device__ __forceinline__ float gelu_tanh(float x){
  float y = 0.7978845608028654f*(x + 0.044715f*x*x*x);
  y = fminf(fmaxf(y, -12.f), 12.f);
  float e = __expf(-2.f*y);
  float t = (1.f - e) / (1.f + e);
  return 0.5f*x*(1.0f + t);
}
__device__ __forceinline__ void gload16(const u16* g, u16* l){
  __builtin_amdgcn_global_load_lds(
      (const __attribute__((address_space(1))) void*)g,
      (__attribute__((address_space(3))) void*)l, 16, 0, 0);
}
#define BAR() do{ asm volatile("":::"memory"); __builtin_amdgcn_s_barrier(); asm volatile("":::"memory"); }while(0)
#define VMW_(n) asm volatile("s_waitcnt vmcnt(" #n ")":::"memory")
#define VMW(n) VMW_(n)
#define VMC0() asm volatile("s_waitcnt vmcnt(0)":::"memory")

// ---------------------------------------------------------------- emb kernels
__global__ __launch_bounds__(256)
void emb_partial(const float* __restrict__ temb, const float* __restrict__ wn,
                 float* __restrict__ partial)
{
  __shared__ float ls[384];
  int tid = threadIdx.x;
  int kb = blockIdx.y * 384;
  for (int i = tid; i < 384; i += 256){
    float t = temb[kb + i];
    ls[i] = t / (1.0f + __expf(-t));
  }
  __syncthreads();
  int j = blockIdx.x*256 + tid;
  const float* wp = wn + (size_t)kb*NEMB + j;
  float acc = 0.f;
  #pragma unroll 8
  for (int i = 0; i < 384; i++){ acc = fmaf(ls[i], wp[0], acc); wp += NEMB; }
  partial[blockIdx.y*NEMB + j] = acc;
}

__global__ __launch_bounds__(256)
void emb_reduce(const float* __restrict__ partial, const float* __restrict__ bn,
                float* __restrict__ emb)
{
  int j = blockIdx.x*256 + threadIdx.x;
  float s = bn[j];
  #pragma unroll
  for (int r = 0; r < 8; r++) s += partial[r*NEMB + j];
  emb[j] = s;
}

// ------------------------------------------------- layernorm + modulate (bf16)
__global__ __launch_bounds__(256)
void ln_mod(const float* __restrict__ hs, const float* __restrict__ ehs,
            const float* __restrict__ emb, u16* __restrict__ nx)
{
  int row = blockIdx.x;
  const float* x = (row < SIMG) ? hs + (size_t)row*HIDDEN
                                : ehs + (size_t)(row - SIMG)*HIDDEN;
  int tid = threadIdx.x;
  float vals[12];
  float s = 0.f, ss = 0.f;
  #pragma unroll
  for (int i = 0; i < 3; i++){
    float4 v = *reinterpret_cast<const float4*>(x + i*1024 + tid*4);
    vals[i*4+0]=v.x; vals[i*4+1]=v.y; vals[i*4+2]=v.z; vals[i*4+3]=v.w;
    s += v.x+v.y+v.z+v.w;
    ss += v.x*v.x + v.y*v.y + v.z*v.z + v.w*v.w;
  }
  #pragma unroll
  for (int d = 1; d < 64; d <<= 1){ s += __shfl_xor(s, d); ss += __shfl_xor(ss, d); }
  __shared__ float red[8];
  if ((tid & 63) == 0){ red[tid>>6] = s; red[4 + (tid>>6)] = ss; }
  __syncthreads();
  s  = red[0]+red[1]+red[2]+red[3];
  ss = red[4]+red[5]+red[6]+red[7];
  float mu = s * (1.0f/HIDDEN);
  float var = ss * (1.0f/HIDDEN) - mu*mu;
  float rs = rsqrtf(var + LN_EPS);
  #pragma unroll
  for (int i = 0; i < 3; i++){
    int col = i*1024 + tid*4;
    u16x4 o;
    #pragma unroll
    for (int j = 0; j < 4; j++){
      float nv = (vals[i*4+j] - mu) * rs;
      float outv = nv * (1.0f + emb[HIDDEN + col + j]) + emb[col + j];
      o[j] = f2us(outv);
    }
    *reinterpret_cast<u16x4*>(nx + (size_t)row*HIDDEN + col) = o;
  }
}

// ------------------------------------------- W[K][N] f32 -> Wt[noff+n][k] bf16
__global__ __launch_bounds__(256)
void transpose_w(const float* __restrict__ W, u16* __restrict__ Wt,
                 int K, int N, int ldt, int noff)
{
  __shared__ float t[64][65];
  const int tid = threadIdx.x;
  const int kb = blockIdx.y * 64, nb = blockIdx.x * 64;
  #pragma unroll
  for (int i = 0; i < 4; i++){
    int row = (tid >> 4) + i*16;
    int c4  = (tid & 15) * 4;
    float4 v = *reinterpret_cast<const float4*>(W + (size_t)(kb+row)*N + nb + c4);
    t[row][c4] = v.x; t[row][c4+1] = v.y; t[row][c4+2] = v.z; t[row][c4+3] = v.w;
  }
  __syncthreads();
  int n  = tid >> 2;
  int kc = (tid & 3) * 16;
  u16 tmp[16];
  #pragma unroll
  for (int j = 0; j < 16; j++) tmp[j] = f2us(t[kc+j][n]);
  u16* dst = Wt + (size_t)(noff + nb + n)*ldt + kb + kc;
  *reinterpret_cast<i32x4*>(dst)     = *reinterpret_cast<const i32x4*>(tmp);
  *reinterpret_cast<i32x4*>(dst + 8) = *reinterpret_cast<const i32x4*>(tmp + 8);
}

// --------------------------------------------------------- 8-phase 256² GEMM
// Same quarter-region ledger as Round 3/4 (proven), but ONE barrier per phase:
// reads complete before each wave's own MFMA issues (compiler fine-grained
// lgkmcnt), which precedes the phase-ending barrier -> read-vs-overwrite is
// still separated by >=2 trailing barriers; staging guarantees propagate at
// the VMW+BAR pairs (phases 2,4). Reads hoisted (12/half-K) so phase B is
// pure MFMA. LDS is the occupancy binder (1 block/CU), so extra VGPR is free.
template<int EPI>
__global__ __launch_bounds__(512, 2)
void gemm8(const u16* __restrict__ A_, int lda,
           const u16* __restrict__ Bt_, int ldb,
           int K, int N, int kspl,
           const float* __restrict__ b0, const float* __restrict__ b1,
           const float* __restrict__ b2, const float* __restrict__ b3,
           u16* __restrict__ qkvo, u16* __restrict__ hcat,
           float* __restrict__ outf)
{
  extern __shared__ __align__(16) u16 lds[];   // 65536 u16 = 128 KiB
  const int tid = threadIdx.x, lane = tid & 63, wid = tid >> 6;
  const int l15 = lane & 15, lhi = lane >> 4;
  const int wm = wid >> 2, wn = wid & 3;
  const int NK = K / 64;    // must be even and >= 6

  const u16* Ag = A_  + (size_t)blockIdx.z * kspl;
  const u16* Bg = Bt_ + (size_t)blockIdx.z * kspl;

  // bijective XCD-aware swizzle (m204), column-major block order
  const int nwg = gridDim.x;
  int orig = blockIdx.x;
  int qq = nwg >> 3, rr = nwg & 7;
  int xcd = orig & 7, loc = orig >> 3;
  int wg = (xcd < rr ? xcd*(qq+1) : rr*(qq+1) + (xcd-rr)*qq) + loc;
  const int m0 = (wg % MB) * 256;
  const int n0 = (wg / MB) * 256;

  // staging global pointers (2 issues per quarter-region per wave)
  const u16 *gA0, *gA1, *gB0, *gB1;
  {
    size_t offA[2], offB[2];
    #pragma unroll
    for (int q = 0; q < 2; q++){
      int Lb = q*8192 + tid*16;          // byte offset within region
      int r  = Lb >> 7;                  // LDS row (128B rows)
      int gp = (Lb >> 4) & 7;
      int g  = gp ^ (r & 7);
      int row = 2*r + (g >> 2);
      int ke  = (g & 3) * 8;
      offA[q] = (size_t)(m0 + row)*lda + ke;
      offB[q] = (size_t)(n0 + row)*ldb + ke;
    }
    gA0 = Ag + offA[0]; gA1 = Ag + offA[1];
    gB0 = Bg + offB[0]; gB1 = Bg + offB[1];
  }
  // staging LDS destinations (elem offsets; region base added as const)
  u16* dA0 = lds + tid*8;
  u16* dA1 = lds + 4096 + tid*8;
  u16* dB0 = lds + 32768 + tid*8;
  u16* dB1 = lds + 36864 + tid*8;

  // precomputed per-lane LDS read pointers (region base folds into offset imm)
  const char* pa[8];
  const char* pb[4];
  {
    const char* LB = (const char*)lds;
    #pragma unroll
    for (int c = 0; c < 2; c++)
      #pragma unroll
      for (int mf = 0; mf < 4; mf++){
        int R = wm*128 + c*64 + mf*16 + l15;
        int off = (R>>1)*128 + (((((R&1)<<2)|lhi) ^ ((R>>1)&7))*16);
        pa[c*4+mf] = LB + off;
      }
    #pragma unroll
    for (int nf = 0; nf < 4; nf++){
      int R = wn*64 + nf*16 + l15;
      int off = (R>>1)*128 + (((((R&1)<<2)|lhi) ^ ((R>>1)&7))*16);
      pb[nf] = LB + 65536 + off;
    }
  }

  f32x4 acc[8][4];
  #pragma unroll
  for (int i = 0; i < 8; i++)
    #pragma unroll
    for (int j = 0; j < 4; j++){ f32x4 z = {0.f,0.f,0.f,0.f}; acc[i][j] = z; }

  #define LD8(P_) (*reinterpret_cast<const s16x8*>(P_))
  #define MFMA_BLK(A0_) do{                                                    \
    _Pragma("unroll") for (int mf_=0; mf_<4; mf_++)                            \
      _Pragma("unroll") for (int nf_=0; nf_<4; nf_++)                          \
        acc[(A0_)+mf_][nf_] = __builtin_amdgcn_mfma_f32_16x16x32_bf16(         \
            af[(A0_)+mf_], bf[nf_], acc[(A0_)+mf_][nf_], 0, 0, 0); }while(0)

  // one K-iter (2 halves x 2 phases, ONE barrier per phase).
  // P_: parity (compile-time). DOE_: issue (j+1,k1). DOL_: issue (j+2,k0).
  #define KBODY(P_,DOE_,DOL_,EOFF_,LOFF_,V2_,V4_) do{                          \
    constexpr int CA0 = (P_)?32768:0, CA1 = (P_)?49152:16384;                  \
    constexpr int ERE = (P_)?8192:24576, LRE = (P_)?16384:0;                   \
    s16x8 af[8], bf[4];                                                        \
    /* half k0, phase A: 12 reads + A-issue + MFMA blk0 */                     \
    _Pragma("unroll") for (int i_=0;i_<8;i_++) af[i_] = LD8(pa[i_]+CA0);       \
    _Pragma("unroll") for (int i_=0;i_<4;i_++) bf[i_] = LD8(pb[i_]+CA0);       \
    if (DOE_){ gload16(gA0+(EOFF_), dA0+ERE); gload16(gA1+(EOFF_), dA1+ERE); } \
    __builtin_amdgcn_s_setprio(1); MFMA_BLK(0); __builtin_amdgcn_s_setprio(0); \
    BAR();                                                                     \
    /* half k0, phase B: B-issue + pure MFMA blk4 */                           \
    if (DOE_){ gload16(gB0+(EOFF_), dB0+ERE); gload16(gB1+(EOFF_), dB1+ERE); } \
    __builtin_amdgcn_s_setprio(1); MFMA_BLK(4); __builtin_amdgcn_s_setprio(0); \
    VMW(V2_); BAR();                                                           \
    /* half k1, phase A */                                                     \
    _Pragma("unroll") for (int i_=0;i_<8;i_++) af[i_] = LD8(pa[i_]+CA1);       \
    _Pragma("unroll") for (int i_=0;i_<4;i_++) bf[i_] = LD8(pb[i_]+CA1);       \
    if (DOL_){ gload16(gA0+(LOFF_), dA0+LRE); gload16(gA1+(LOFF_), dA1+LRE); } \
    __builtin_amdgcn_s_setprio(1); MFMA_BLK(0); __builtin_amdgcn_s_setprio(0); \
    BAR();                                                                     \
    /* half k1, phase B */                                                     \
    if (DOL_){ gload16(gB0+(LOFF_), dB0+LRE); gload16(gB1+(LOFF_), dB1+LRE); } \
    __builtin_amdgcn_s_setprio(1); MFMA_BLK(4); __builtin_amdgcn_s_setprio(0); \
    VMW(V4_); BAR();                                                           \
  }while(0)

  // prologue: A(0,0) B(0,0) A(0,1) B(0,1) A(1,0) B(1,0)  (12 loads)
  gload16(gA0,    dA0);         gload16(gA1,    dA1);
  gload16(gB0,    dB0);         gload16(gB1,    dB1);
  gload16(gA0+32, dA0+8192);    gload16(gA1+32, dA1+8192);
  gload16(gB0+32, dB0+8192);    gload16(gB1+32, dB1+8192);
  gload16(gA0+64, dA0+16384);   gload16(gA1+64, dA1+16384);
  gload16(gB0+64, dB0+16384);   gload16(gB1+64, dB1+16384);
  VMW(8);
  BAR();

  for (int jj = 0; jj + 3 < NK; jj += 2){
    KBODY(0, 1, 1,  96, 128, 8, 8);
    KBODY(1, 1, 1, 160, 192, 8, 8);
    gA0 += 128; gA1 += 128; gB0 += 128; gB1 += 128;
  }
  // tail: j = NK-2 (parity 0): issue only (NK-1,k1); vmcnt 8 then 4
  KBODY(0, 1, 0, 96, 0, 8, 4);
  // tail: j = NK-1 (parity 1): no issues; full drain mid-iter
  KBODY(1, 0, 0, 0, 0, 0, 0);
  VMC0();

  #undef KBODY
  #undef MFMA_BLK
  #undef LD8

  // epilogue
  #pragma unroll
  for (int a = 0; a < 8; a++){
    #pragma unroll
    for (int nf = 0; nf < 4; nf++){
      int col = n0 + wn*64 + nf*16 + l15;
      #pragma unroll
      for (int r = 0; r < 4; r++){
        int row = m0 + wm*128 + a*16 + lhi*4 + r;
        float v = acc[a][nf][r];
        if constexpr (EPI == 0){
          if (col < QKVD){
            const float* bp = b0; int c = col;
            if (c >= 6144){ bp = b2; c -= 6144; }
            else if (c >= 3072){ bp = b1; c -= 3072; }
            qkvo[(size_t)row*QKVD + col] = f2us(v + bp[c]);
          } else {
            int c2 = col - QKVD;
            hcat[(size_t)row*CATD + HIDDEN + c2] = f2us(gelu_tanh(v + b3[c2]));
          }
        } else {
          outf[(size_t)blockIdx.z*NTOK*HIDDEN + (size_t)row*HIDDEN + col] = v;
        }
      }
    }
  }
}

// ------------------------------------- split-K reduce + gate/residual epilogue
__global__ __launch_bounds__(256)
void reduce_out(const float* __restrict__ part, const float* __restrict__ bout,
                const float* __restrict__ emb,
                const float* __restrict__ hs, const float* __restrict__ ehs,
                float* __restrict__ outp)
{
  int row = blockIdx.x;
  const float* res = (row < SIMG) ? hs + (size_t)row*HIDDEN
                                  : ehs + (size_t)(row - SIMG)*HIDDEN;
  #pragma unroll
  for (int i = 0; i < 3; i++){
    int col = i*1024 + threadIdx.x*4;
    float4 a = *reinterpret_cast<const float4*>(part + (size_t)row*HIDDEN + col);
    float4 b = *reinterpret_cast<const float4*>(part + (size_t)NTOK*HIDDEN + (size_t)row*HIDDEN + col);
    float4 rr = *reinterpret_cast<const float4*>(res + col);
    float4 bb = *reinterpret_cast<const float4*>(bout + col);
    float4 gg = *reinterpret_cast<const float4*>(emb + 2*HIDDEN + col);
    float4 o;
    o.x = gg.x*(a.x+b.x+bb.x) + rr.x;
    o.y = gg.y*(a.y+b.y+bb.y) + rr.y;
    o.z = gg.z*(a.z+b.z+bb.z) + rr.z;
    o.w = gg.w*(a.w+b.w+bb.w) + rr.w;
    *reinterpret_cast<float4*>(outp + (size_t)row*HIDDEN + col) = o;
  }
}

// ------------------------------------------- rmsnorm + rope on q,k (in place)
__global__ __launch_bounds__(256)
void qk_post(u16* __restrict__ qkv,
             const float* __restrict__ nqw, const float* __restrict__ nkw,
             const float* __restrict__ fc)
{
  int rid = blockIdx.x*4 + (threadIdx.x >> 6);
  int lane = threadIdx.x & 63;
  int isK = rid >= NTOK*HEADS;
  int r = isK ? rid - NTOK*HEADS : rid;
  int token = r / HEADS, head = r % HEADS;
  u16* p = qkv + (size_t)token*QKVD + (isK ? HIDDEN : 0) + head*HD + lane*2;
  unsigned int u = *reinterpret_cast<unsigned int*>(p);
  float v0 = us2f((u16)(u & 0xffff));
  float v1 = us2f((u16)(u >> 16));
  float ss = v0*v0 + v1*v1;
  #pragma unroll
  for (int d = 1; d < 64; d <<= 1) ss += __shfl_xor(ss, d);
  float rs = rsqrtf(ss * (1.0f/HD) + LN_EPS);
  const float* wv = isK ? nkw : nqw;
  v0 *= rs * wv[lane*2];
  v1 *= rs * wv[lane*2+1];
  if (token < SIMG){
    const float* f = fc + (size_t)token*(2*HD);
    float c0 = f[lane*2],      c1 = f[lane*2+1];
    float s0 = f[HD + lane*2], s1 = f[HD + lane*2+1];
    float o0 = v0*c0 - v1*s0;
    float o1 = v1*c1 + v0*s1;
    v0 = o0; v1 = o1;
  }
  unsigned int uo = (unsigned int)f2us(v0) | ((unsigned int)f2us(v1) << 16);
  *reinterpret_cast<unsigned int*>(p) = uo;
}

// ------------------------------------------------------------ flash attention
__global__ __launch_bounds__(256)
void attn_kernel(const u16* __restrict__ qkv, u16* __restrict__ hcat)
{
  __shared__ __align__(16) u16 Qs[64][136];
  __shared__ __align__(16) u16 Ks[64][136];
  __shared__ __align__(16) u16 Vt[128][72];
  __shared__ __align__(16) u16 Ps[64][72];

  const int tid = threadIdx.x, lane = tid & 63, w = tid >> 6;
  const int head = blockIdx.y, qb = blockIdx.x;
  const int l15 = lane & 15, lhi = lane >> 4;
  const int q0 = qb * 64;
  const float scale = 0.08838834764831845f;

  #pragma unroll
  for (int i = 0; i < 4; i++){
    int c = tid + 256*i;
    int row = c >> 4, d0 = (c & 15) * 8;
    i32x4 vv = *reinterpret_cast<const i32x4*>(qkv + (size_t)(q0+row)*QKVD + head*HD + d0);
    *reinterpret_cast<i32x4*>(&Qs[row][d0]) = vv;
  }

  f32x4 O[8];
  #pragma unroll
  for (int i = 0; i < 8; i++){ f32x4 z = {0.f,0.f,0.f,0.f}; O[i] = z; }
  float mrow[4], lrow[4];
  #pragma unroll
  for (int r = 0; r < 4; r++){ mrow[r] = -1e30f; lrow[r] = 0.f; }

  for (int kv0 = 0; kv0 < NTOK; kv0 += 64){
    #pragma unroll
    for (int i = 0; i < 4; i++){
      int c = tid + 256*i;
      int row = c >> 4, d0 = (c & 15) * 8;
      i32x4 vv = *reinterpret_cast<const i32x4*>(qkv + (size_t)(kv0+row)*QKVD + HIDDEN + head*HD + d0);
      *reinterpret_cast<i32x4*>(&Ks[row][d0]) = vv;
    }
    #pragma unroll
    for (int i = 0; i < 4; i++){
      int c = tid + 256*i;
      int kvr = c >> 4, d0 = (c & 15) * 8;
      i32x4 vv = *reinterpret_cast<const i32x4*>(qkv + (size_t)(kv0+kvr)*QKVD + 2*HIDDEN + head*HD + d0);
      const u16* pv = reinterpret_cast<const u16*>(&vv);
      #pragma unroll
      for (int j = 0; j < 8; j++){
        int d = d0 + j;
        int col = (((kvr>>3) ^ ((d>>3)&7)) << 3) | (kvr & 7);
        Vt[d][col] = pv[j];
      }
    }
    __syncthreads();

    f32x4 S[4];
    #pragma unroll
    for (int nf = 0; nf < 4; nf++){ f32x4 z = {0.f,0.f,0.f,0.f}; S[nf] = z; }
    #pragma unroll
    for (int ks = 0; ks < 4; ks++){
      s16x8 a = *reinterpret_cast<const s16x8*>(&Qs[w*16 + l15][ks*32 + lhi*8]);
      #pragma unroll
      for (int nf = 0; nf < 4; nf++){
        s16x8 b = *reinterpret_cast<const s16x8*>(&Ks[nf*16 + l15][ks*32 + lhi*8]);
        S[nf] = __builtin_amdgcn_mfma_f32_16x16x32_bf16(a, b, S[nf], 0, 0, 0);
      }
    }
    #pragma unroll
    for (int nf = 0; nf < 4; nf++)
      #pragma unroll
      for (int r = 0; r < 4; r++) S[nf][r] *= scale;

    float fsc[4];
    #pragma unroll
    for (int r = 0; r < 4; r++){
      float mx = -1e30f;
      #pragma unroll
      for (int nf = 0; nf < 4; nf++) mx = fmaxf(mx, S[nf][r]);
      #pragma unroll
      for (int d = 1; d < 16; d <<= 1) mx = fmaxf(mx, __shfl_xor(mx, d));
      float mn = fmaxf(mrow[r], mx);
      float f = __expf(mrow[r] - mn);
      mrow[r] = mn; fsc[r] = f;
      float lsum = 0.f;
      int prow = w*16 + lhi*4 + r;
      #pragma unroll
      for (int nf = 0; nf < 4; nf++){
        float pvl = __expf(S[nf][r] - mn);
        lsum += pvl;
        int pcol = nf*16 + l15;
        int col = (((pcol>>3) ^ (prow&7)) << 3) | (pcol & 7);
        Ps[prow][col] = f2us(pvl);
      }
      #pragma unroll
      for (int d = 1; d < 16; d <<= 1) lsum += __shfl_xor(lsum, d);
      lrow[r] = lrow[r]*f + lsum;
    }
    #pragma unroll
    for (int nf = 0; nf < 8; nf++)
      #pragma unroll
      for (int r = 0; r < 4; r++) O[nf][r] *= fsc[r];
    __syncthreads();

    #pragma unroll
    for (int ks = 0; ks < 2; ks++){
      int prow = w*16 + l15;
      int cb = ((ks*4 + lhi) ^ (prow & 7)) << 3;
      s16x8 a = *reinterpret_cast<const s16x8*>(&Ps[prow][cb]);
      #pragma unroll
      for (int nf = 0; nf < 8; nf++){
        int d = nf*16 + l15;
        int vb = ((ks*4 + lhi) ^ ((d>>3)&7)) << 3;
        s16x8 b = *reinterpret_cast<const s16x8*>(&Vt[d][vb]);
        O[nf] = __builtin_amdgcn_mfma_f32_16x16x32_bf16(a, b, O[nf], 0, 0, 0);
      }
    }
    __syncthreads();
  }

  #pragma unroll
  for (int nf = 0; nf < 8; nf++){
    #pragma unroll
    for (int r = 0; r < 4; r++){
      int row = q0 + w*16 + lhi*4 + r;
      int col = head*HD + nf*16 + l15;
      hcat[(size_t)row*CATD + col] = f2us(O[nf][r] / lrow[r]);
    }
  }
}

// ---------------------------------------------------------------------- host
extern "C" void kernel_launch(void* const* d_in, const int* in_sizes, int n_in,
                              void* d_out, int out_size, void* d_ws, size_t ws_size,
                              hipStream_t stream)
{
  const float* hs    = (const float*)d_in[0];
  const float* ehs   = (const float*)d_in[1];
  const float* temb  = (const float*)d_in[2];
  const float* fc    = (const float*)d_in[3];
  const float* wnorm = (const float*)d_in[4];
  const float* bnorm = (const float*)d_in[5];
  const float* wq    = (const float*)d_in[6];
  const float* bq    = (const float*)d_in[7];
  const float* wk    = (const float*)d_in[8];
  const float* bk    = (const float*)d_in[9];
  const float* wv    = (const float*)d_in[10];
  const float* bv    = (const float*)d_in[11];
  const float* nqw   = (const float*)d_in[12];
  const float* nkw   = (const float*)d_in[13];
  const float* wmlp  = (const float*)d_in[14];
  const float* bmlp  = (const float*)d_in[15];
  const float* wout  = (const float*)d_in[16];
  const float* bout  = (const float*)d_in[17];
  float* outp = (float*)d_out;

  char* ws = (char*)d_ws;
  float* emb  = (float*)ws;                               // 36864 B
  float* part = (float*)(ws + 36864);                     // 294912 B
  u16* nx     = (u16*)(ws + 36864 + 294912);              // 14,155,776 B
  u16* qkv    = nx  + (size_t)NTOK*HIDDEN;                // 42,467,328 B
  u16* hcat   = qkv + (size_t)NTOK*QKVD;                  // 70,778,880 B
  u16* Wt     = hcat + (size_t)NTOK*CATD;                 // 132,120,576 B
  float* partial = (float*)nx;  // aliases nx+qkv (dead by out-proj time)

  hipFuncSetAttribute((const void*)gemm8<0>, hipFuncAttributeMaxDynamicSharedMemorySize, 131072);
  hipFuncSetAttribute((const void*)gemm8<1>, hipFuncAttributeMaxDynamicSharedMemorySize, 131072);

  emb_partial<<<dim3(36,8), 256, 0, stream>>>(temb, wnorm, part);
  emb_reduce<<<36, 256, 0, stream>>>(part, bnorm, emb);
  ln_mod<<<NTOK, 256, 0, stream>>>(hs, ehs, emb, nx);

  // Wt rows: [0,9216) = q|k|v ; [9216,21504) = mlp ; ldt = 3072
  transpose_w<<<dim3(48,48), 256, 0, stream>>>(wq,   Wt, HIDDEN, HIDDEN, HIDDEN, 0);
  transpose_w<<<dim3(48,48), 256, 0, stream>>>(wk,   Wt, HIDDEN, HIDDEN, HIDDEN, HIDDEN);
  transpose_w<<<dim3(48,48), 256, 0, stream>>>(wv,   Wt, HIDDEN, HIDDEN, HIDDEN, 2*HIDDEN);
  transpose_w<<<dim3(192,48), 256, 0, stream>>>(wmlp, Wt, HIDDEN, MLPD, HIDDEN, QKVD);

  // fused QKV+MLP GEMM: [2304 x 21504], K=3072 (NK=48)
  gemm8<0><<<dim3((FUSEN/256)*MB, 1, 1), 512, 131072, stream>>>(
      nx, HIDDEN, Wt, HIDDEN, HIDDEN, FUSEN, 0,
      bq, bk, bv, bmlp, qkv, hcat, nullptr);

  // out-proj weights: Wt[3072][15360] (reuses Wt region)
  transpose_w<<<dim3(48,240), 256, 0, stream>>>(wout, Wt, CATD, HIDDEN, CATD, 0);

  qk_post<<<(2*NTOK*HEADS)/4, 256, 0, stream>>>(qkv, nqw, nkw, fc);
  attn_kernel<<<dim3(NTOK/64, HEADS), 256, 0, stream>>>(qkv, hcat);

  // out-proj: split-K=2 (NK=120 each), f32 partials
  gemm8<1><<<dim3((HIDDEN/256)*MB, 1, 2), 512, 131072, stream>>>(
      hcat, CATD, Wt, CATD, CATD/2, HIDDEN, CATD/2,
      nullptr, nullptr, nullptr, nullptr, nullptr, nullptr, partial);

  reduce_out<<<NTOK, 256, 0, stream>>>(partial, bout, emb, hs, ehs, outp);
}